// Round 10
// baseline (918.601 us; speedup 1.0000x reference)
//
#include <hip/hip_runtime.h>

typedef _Float16 f16;
typedef _Float16 f16x8 __attribute__((ext_vector_type(8)));
typedef _Float16 f16x4 __attribute__((ext_vector_type(4)));
typedef float f32x4 __attribute__((ext_vector_type(4)));

#define MFMA16(A,B,C) __builtin_amdgcn_mfma_f32_16x16x32_f16(A,B,C,0,0,0)
#define INV2048 4.8828125e-4f
#define HN (16ll*2048*96)
#define UVN 589824   // 768*768
// z in log2 domain: zl = log2(e)*768*accS + log2(e)*768/2048*accX
#define ZC1 1107.98979f
#define ZC2 0.54101064f

__device__ __forceinline__ void split_f16(float x, f16& h, f16& l) {
    h = (f16)x;
    l = (f16)((x - (float)h) * 2048.0f);   // lo pre-scaled by 2^11 (avoids fp16 denorm loss)
}

// ============================================================
// K0: split qz, U, V (fp32) into fp16 hi/lo pairs. (unchanged)
// ============================================================
__global__ __launch_bounds__(256) void k0_split(const float* __restrict__ qz,
                                                const float* __restrict__ U,
                                                const float* __restrict__ V,
                                                f16* __restrict__ qzh, f16* __restrict__ qzl,
                                                f16* __restrict__ Uh, f16* __restrict__ Ul,
                                                f16* __restrict__ Vh, f16* __restrict__ Vl) {
    const int i4 = blockIdx.x * 256 + threadIdx.x;   // float4 index
    {
        float4 x = *(const float4*)(qz + (size_t)i4 * 4);
        f16 h0, l0, h1, l1, h2, l2, h3, l3;
        split_f16(x.x, h0, l0); split_f16(x.y, h1, l1);
        split_f16(x.z, h2, l2); split_f16(x.w, h3, l3);
        f16x4 hv = {h0, h1, h2, h3};
        f16x4 lv = {l0, l1, l2, l3};
        *(f16x4*)(qzh + (size_t)i4 * 4) = hv;
        *(f16x4*)(qzl + (size_t)i4 * 4) = lv;
    }
    if (i4 < UVN / 4) {
        float4 x = *(const float4*)(U + (size_t)i4 * 4);
        f16 h0, l0, h1, l1, h2, l2, h3, l3;
        split_f16(x.x, h0, l0); split_f16(x.y, h1, l1);
        split_f16(x.z, h2, l2); split_f16(x.w, h3, l3);
        f16x4 hv = {h0, h1, h2, h3};
        f16x4 lv = {l0, l1, l2, l3};
        *(f16x4*)(Uh + (size_t)i4 * 4) = hv;
        *(f16x4*)(Ul + (size_t)i4 * 4) = lv;
        float4 y = *(const float4*)(V + (size_t)i4 * 4);
        split_f16(y.x, h0, l0); split_f16(y.y, h1, l1);
        split_f16(y.z, h2, l2); split_f16(y.w, h3, l3);
        f16x4 hv2 = {h0, h1, h2, h3};
        f16x4 lv2 = {l0, l1, l2, l3};
        *(f16x4*)(Vh + (size_t)i4 * 4) = hv2;
        *(f16x4*)(Vl + (size_t)i4 * 4) = lv2;
    }
}

// ============================================================
// K1: dual GEMM qz@U^T, qz@V^T via fp16 MFMA 3-product emulation
// + RoPE. + XCD-chunked block swizzle. (unchanged, round-8)
// ============================================================
__global__ __launch_bounds__(256, 2) void k1_proj(const f16* __restrict__ qzh,
                                                  const f16* __restrict__ qzl,
                                                  const f16* __restrict__ Uh,
                                                  const f16* __restrict__ Ul,
                                                  const f16* __restrict__ Vh,
                                                  const f16* __restrict__ Vl,
                                                  const float* __restrict__ cosb,
                                                  const float* __restrict__ sinb,
                                                  f16* __restrict__ uhp, f16* __restrict__ ulp,
                                                  f16* __restrict__ vhp, f16* __restrict__ vlp,
                                                  f16* __restrict__ vT, f16* __restrict__ oT) {
    __shared__ __align__(16) f16 smem[36864];            // 73728 B -> 2 blocks/CU
    f16* sAh  = smem;                                    // [64][72]
    f16* sAl  = smem + 4608;
    f16* sBuh = smem + 9216;                             // [96][72]
    f16* sBul = smem + 9216 + 6912;
    f16* sBvh = smem + 9216 + 2 * 6912;
    f16* sBvl = smem + 9216 + 3 * 6912;

    const int tid = threadIdx.x;
    const int w = tid >> 6, lane = tid & 63;
    const int quad = lane >> 4, l15 = lane & 15;
    const int wr = w >> 1, wc = w & 1;                   // 2x2 wave grid
    const int bid0 = blockIdx.y * 64 + blockIdx.x;
    const int swz  = (bid0 & 7) * 64 + (bid0 >> 3);
    const int bs0 = (swz & 63) * 64;
    const int c = swz >> 6;

    const f16* Ug_h = Uh + (size_t)c * 96 * 768;
    const f16* Ug_l = Ul + (size_t)c * 96 * 768;
    const f16* Vg_h = Vh + (size_t)c * 96 * 768;
    const f16* Vg_l = Vl + (size_t)c * 96 * 768;

    f32x4 aUS[2][3] = {}, aUX[2][3] = {};
    f32x4 aVS[2][3] = {}, aVX[2][3] = {};

    for (int k0 = 0; k0 < 768; k0 += 64) {
        __syncthreads();
#pragma unroll
        for (int m = 0; m < 2; ++m) {
            int f = tid + 256 * m, row = f >> 3, cg = f & 7;
            const size_t go = (size_t)(bs0 + row) * 768 + k0 + cg * 8;
            const int lo = row * 72 + cg * 8;
            *(float4*)&sAh[lo] = *(const float4*)(qzh + go);
            *(float4*)&sAl[lo] = *(const float4*)(qzl + go);
        }
#pragma unroll
        for (int m = 0; m < 3; ++m) {
            int f = tid + 256 * m, row = f >> 3, cg = f & 7;
            const size_t go = (size_t)row * 768 + k0 + cg * 8;
            const int lo = row * 72 + cg * 8;
            *(float4*)&sBuh[lo] = *(const float4*)(Ug_h + go);
            *(float4*)&sBul[lo] = *(const float4*)(Ug_l + go);
            *(float4*)&sBvh[lo] = *(const float4*)(Vg_h + go);
            *(float4*)&sBvl[lo] = *(const float4*)(Vg_l + go);
        }
        __syncthreads();
#pragma unroll
        for (int cc = 0; cc < 2; ++cc) {
            f16x8 ah[2], al[2];
#pragma unroll
            for (int mt = 0; mt < 2; ++mt) {
                const int ar = (32 * wr + 16 * mt + l15) * 72 + cc * 32 + quad * 8;
                ah[mt] = *(const f16x8*)&sAh[ar];
                al[mt] = *(const f16x8*)&sAl[ar];
            }
#pragma unroll
            for (int nt = 0; nt < 3; ++nt) {
                const int br = (48 * wc + 16 * nt + l15) * 72 + cc * 32 + quad * 8;
                f16x8 buh = *(const f16x8*)&sBuh[br];
                f16x8 bul = *(const f16x8*)&sBul[br];
                f16x8 bvh = *(const f16x8*)&sBvh[br];
                f16x8 bvl = *(const f16x8*)&sBvl[br];
#pragma unroll
                for (int mt = 0; mt < 2; ++mt) {
                    aUS[mt][nt] = MFMA16(ah[mt], buh, aUS[mt][nt]);
                    aUX[mt][nt] = MFMA16(ah[mt], bul, aUX[mt][nt]);
                    aUX[mt][nt] = MFMA16(al[mt], buh, aUX[mt][nt]);
                    aVS[mt][nt] = MFMA16(ah[mt], bvh, aVS[mt][nt]);
                    aVX[mt][nt] = MFMA16(ah[mt], bvl, aVX[mt][nt]);
                    aVX[mt][nt] = MFMA16(al[mt], bvh, aVX[mt][nt]);
                }
            }
        }
    }

    __syncthreads();
    float* LU = (float*)smem;          // [64][100] = 25.6 KB
    float* LV = LU + 6400;
#pragma unroll
    for (int mt = 0; mt < 2; ++mt)
#pragma unroll
        for (int nt = 0; nt < 3; ++nt)
#pragma unroll
            for (int r = 0; r < 4; ++r) {
                const int sl = 32 * wr + 16 * mt + 4 * quad + r;
                const int col = 48 * wc + 16 * nt + l15;
                LU[sl * 100 + col] = aUS[mt][nt][r] + aUX[mt][nt][r] * INV2048;
                LV[sl * 100 + col] = aVS[mt][nt][r] + aVX[mt][nt][r] * INV2048;
            }
    __syncthreads();

    const int b = bs0 >> 11;
    const int s0 = bs0 & 2047;
    const int head = b * 8 + c;
    const size_t nb = (size_t)head * 2048 * 96;
    const size_t tb = (size_t)head * 96 * 2048;
    const int ty = tid >> 4, tx = tid & 15;

#pragma unroll
    for (int jj = 0; jj < 3; ++jj) {
        int r = tx + 16 * jj;
        f16 vt1[4], vt2[4], ot1[4], ot2[4];
#pragma unroll
        for (int ii = 0; ii < 4; ++ii) {
            int sl = 4 * ty + ii;
            int s = s0 + sl;
            int cbi = (b * 2048 + s) * 96 + r;
            float cc = cosb[cbi], ss = sinb[cbi];
            size_t rowb = nb + (size_t)s * 96;
            float u1 = LU[sl * 100 + r], u2 = LU[sl * 100 + r + 48];
            float v1 = LV[sl * 100 + r], v2 = LV[sl * 100 + r + 48];
            float ur1 = u1 * cc - u2 * ss, ur2 = u2 * cc + u1 * ss;
            float uo1 = u1 * cc + u2 * ss, uo2 = u2 * cc - u1 * ss;
            float vr1 = v1 * cc - v2 * ss, vr2 = v2 * cc + v1 * ss;
            f16 h, l;
            split_f16(ur1, h, l); uhp[rowb + r] = h;      ulp[rowb + r] = l;
            split_f16(ur2, h, l); uhp[rowb + r + 48] = h; ulp[rowb + r + 48] = l;
            split_f16(vr1, h, l); vhp[rowb + r] = h;      vlp[rowb + r] = l;      vt1[ii] = h;
            split_f16(vr2, h, l); vhp[rowb + r + 48] = h; vlp[rowb + r + 48] = l; vt2[ii] = h;
            ot1[ii] = (f16)uo1; ot2[ii] = (f16)uo2;
        }
        f16x4 pv1 = {vt1[0], vt1[1], vt1[2], vt1[3]};
        f16x4 pv2 = {vt2[0], vt2[1], vt2[2], vt2[3]};
        f16x4 po1 = {ot1[0], ot1[1], ot1[2], ot1[3]};
        f16x4 po2 = {ot2[0], ot2[1], ot2[2], ot2[3]};
        *(f16x4*)&vT[tb + (size_t)r * 2048 + s0 + 4 * ty] = pv1;
        *(f16x4*)&vT[tb + (size_t)(r + 48) * 2048 + s0 + 4 * ty] = pv2;
        *(f16x4*)&oT[tb + (size_t)r * 2048 + s0 + 4 * ty] = po1;
        *(f16x4*)&oT[tb + (size_t)(r + 48) * 2048 + s0 + 4 * ty] = po2;
    }
}

// ============================================================
// K2: row MAX, k-split x2 and q-split x2 (grid 2048, 4 blocks/CU).
// Each block: 32 q-rows x 16 k-tiles, partial max -> Moa/Mob.
// Direct global B-frags, no LDS in loop, no barriers.
// ============================================================
__global__ __launch_bounds__(256, 4) void k2_stats(const f16* __restrict__ uhp,
                                                   const f16* __restrict__ ulp,
                                                   const f16* __restrict__ vhp,
                                                   const f16* __restrict__ vlp,
                                                   float* __restrict__ Moa,
                                                   float* __restrict__ Mob) {
    __shared__ float Mbuf[4][32];
    const int tid = threadIdx.x, w = tid >> 6, lane = tid & 63;
    const int quad = lane >> 4, l15 = lane & 15;
    const int bid0 = blockIdx.y * 128 + blockIdx.x;      // 0..2047
    const int swz  = (bid0 & 7) * 256 + (bid0 >> 3);     // XCD-chunked, bijective
    const int q0 = (swz & 63) * 32;
    const int head = (swz >> 6) & 15;
    const int half = swz >> 10;
    const f16* Ah_g = uhp + (size_t)head * 2048 * 96;
    const f16* Al_g = ulp + (size_t)head * 2048 * 96;

    f16x8 Afh[2][3], Afl[2][3];
#pragma unroll
    for (int mt = 0; mt < 2; ++mt)
#pragma unroll
        for (int cc = 0; cc < 3; ++cc) {
            size_t off = (size_t)(q0 + 16 * mt + l15) * 96 + cc * 32 + quad * 8;
            Afh[mt][cc] = *(const f16x8*)(Ah_g + off);
            Afl[mt][cc] = *(const f16x8*)(Al_g + off);
        }

    const f16* Bh_p = vhp + (size_t)head * 2048 * 96 +
                      (size_t)(half * 1024 + w * 16 + l15) * 96 + quad * 8;
    const f16* Bl_p = vlp + (size_t)head * 2048 * 96 +
                      (size_t)(half * 1024 + w * 16 + l15) * 96 + quad * 8;

    f16x8 Bch[2][3], Bcl[2][3];
#pragma unroll
    for (int cc = 0; cc < 3; ++cc) {
        Bch[0][cc] = *(const f16x8*)(Bh_p + cc * 32);
        Bcl[0][cc] = *(const f16x8*)(Bl_p + cc * 32);
    }

    float m_run[2][4];
#pragma unroll
    for (int mt = 0; mt < 2; ++mt)
#pragma unroll
        for (int r = 0; r < 4; ++r) m_run[mt][r] = -3.0e38f;

    for (int tp = 0; tp < 8; ++tp) {
#pragma unroll
        for (int h = 0; h < 2; ++h) {
            const int t = 2 * tp + h;
            if (t < 15) {
                const f16* bh = Bh_p + (size_t)(t + 1) * 6144;
                const f16* bl = Bl_p + (size_t)(t + 1) * 6144;
#pragma unroll
                for (int cc = 0; cc < 3; ++cc) {
                    Bch[h ^ 1][cc] = *(const f16x8*)(bh + cc * 32);
                    Bcl[h ^ 1][cc] = *(const f16x8*)(bl + cc * 32);
                }
            }
            f32x4 accS[2] = {}, accX[2] = {};
            __builtin_amdgcn_s_setprio(1);
#pragma unroll
            for (int cc = 0; cc < 3; ++cc)
#pragma unroll
                for (int mt = 0; mt < 2; ++mt) {
                    accS[mt] = MFMA16(Afh[mt][cc], Bch[h][cc], accS[mt]);
                    accX[mt] = MFMA16(Afh[mt][cc], Bcl[h][cc], accX[mt]);
                    accX[mt] = MFMA16(Afl[mt][cc], Bch[h][cc], accX[mt]);
                }
            __builtin_amdgcn_s_setprio(0);
#pragma unroll
            for (int mt = 0; mt < 2; ++mt)
#pragma unroll
                for (int r = 0; r < 4; ++r) {
                    float zl = fmaf(ZC1, accS[mt][r], ZC2 * accX[mt][r]);
                    m_run[mt][r] = fmaxf(m_run[mt][r], zl);
                }
        }
    }
#pragma unroll
    for (int mt = 0; mt < 2; ++mt)
#pragma unroll
        for (int r = 0; r < 4; ++r) {
            float m = m_run[mt][r];
            m = fmaxf(m, __shfl_xor(m, 1)); m = fmaxf(m, __shfl_xor(m, 2));
            m = fmaxf(m, __shfl_xor(m, 4)); m = fmaxf(m, __shfl_xor(m, 8));
            m_run[mt][r] = m;
        }
    if (l15 == 0) {
#pragma unroll
        for (int mt = 0; mt < 2; ++mt)
#pragma unroll
            for (int r = 0; r < 4; ++r)
                Mbuf[w][16 * mt + 4 * quad + r] = m_run[mt][r];
    }
    __syncthreads();
    if (tid < 32) {
        float M = -3.0e38f;
#pragma unroll
        for (int ww = 0; ww < 4; ++ww) M = fmaxf(M, Mbuf[ww][tid]);
        float* Mo_h = half ? Mob : Moa;
        Mo_h[head * 2048 + q0 + tid] = M;    // per-half partial max
    }
}

// ============================================================
// K3a: k-split x2 (grid 1024, 16 k-tiles/block). q-tile stays 64
// (round-8 geometry, staging-per-output unchanged). S=ur.vr^T,
// P=exp2(zl - max(Moa,Mob)), partial PV (+ones column -> partial L).
// Writes raw fp32 accO to Oa/Ob and L to La/Lb; finalize in fa.
// Direct-global B, P+Vt dbuf, 1 barrier/tile, rotated P swizzle.
// ============================================================
__global__ __launch_bounds__(256, 3) void k3a(const f16* __restrict__ uhp,
                                              const f16* __restrict__ ulp,
                                              const f16* __restrict__ vhp,
                                              const f16* __restrict__ vlp,
                                              const f16* __restrict__ vT,
                                              const float* __restrict__ Moa,
                                              const float* __restrict__ Mob,
                                              float* __restrict__ Oa,
                                              float* __restrict__ Ob,
                                              float* __restrict__ La,
                                              float* __restrict__ Lb) {
    __shared__ f16 Vt[2][112 * 72];    // rows 96..111 = ones (row-sum block)
    __shared__ f16 P[2][64 * 72];
    const int tid = threadIdx.x, w = tid >> 6, lane = tid & 63;
    const int quad = lane >> 4, l15 = lane & 15;
    const int bid0 = blockIdx.y * 64 + blockIdx.x;       // 0..1023
    const int swz  = (bid0 & 7) * 128 + (bid0 >> 3);     // XCD-chunked, bijective
    const int q0 = (swz & 31) * 64;
    const int head = (swz >> 5) & 15;
    const int half = swz >> 9;
    const int kb = half * 1024;                          // k-row base
    const f16* Ah_g = uhp + (size_t)head * 2048 * 96;
    const f16* Al_g = ulp + (size_t)head * 2048 * 96;
    const f16* Vt_g = vT + (size_t)head * 96 * 2048;

    f16x8 Afh[4][3], Afl[4][3];
#pragma unroll
    for (int mt = 0; mt < 4; ++mt)
#pragma unroll
        for (int cc = 0; cc < 3; ++cc) {
            size_t off = (size_t)(q0 + 16 * mt + l15) * 96 + cc * 32 + quad * 8;
            Afh[mt][cc] = *(const f16x8*)(Ah_g + off);
            Afl[mt][cc] = *(const f16x8*)(Al_g + off);
        }
    float negM[4][4];
#pragma unroll
    for (int mt = 0; mt < 4; ++mt)
#pragma unroll
        for (int r = 0; r < 4; ++r) {
            int i = head * 2048 + q0 + 16 * mt + 4 * quad + r;
            negM[mt][r] = -fmaxf(Moa[i], Mob[i]);
        }

    const f16* Bh_p = vhp + (size_t)head * 2048 * 96 +
                      (size_t)(kb + w * 16 + l15) * 96 + quad * 8;
    const f16* Bl_p = vlp + (size_t)head * 2048 * 96 +
                      (size_t)(kb + w * 16 + l15) * 96 + quad * 8;
    const int vr0 = tid >> 3, vc8 = (tid & 7) * 8;       // Vt rows vr0,+32,+64
    const int pwc = (w * 16 + l15 + 16 * quad) & 63;     // P write col (rotated)
    const int prr = 16 * (l15 >> 2);                     // P read rotation

    if (tid < 144) {
        f16x8 ones = {(f16)1, (f16)1, (f16)1, (f16)1,
                      (f16)1, (f16)1, (f16)1, (f16)1};
        *(f16x8*)&Vt[0][96 * 72 + tid * 8] = ones;
        *(f16x8*)&Vt[1][96 * 72 + tid * 8] = ones;
    }

    f16x8 Bch[2][3], Bcl[2][3];
    float4 v0, v1, v2;
#pragma unroll
    for (int cc = 0; cc < 3; ++cc) {
        Bch[0][cc] = *(const f16x8*)(Bh_p + cc * 32);
        Bcl[0][cc] = *(const f16x8*)(Bl_p + cc * 32);
    }
    v0 = *(const float4*)(Vt_g + (size_t)vr0 * 2048 + kb + vc8);
    v1 = *(const float4*)(Vt_g + (size_t)(vr0 + 32) * 2048 + kb + vc8);
    v2 = *(const float4*)(Vt_g + (size_t)(vr0 + 64) * 2048 + kb + vc8);
    *(float4*)&Vt[0][vr0 * 72 + vc8] = v0;
    *(float4*)&Vt[0][(vr0 + 32) * 72 + vc8] = v1;
    *(float4*)&Vt[0][(vr0 + 64) * 72 + vc8] = v2;

    f32x4 accO[7] = {};

    for (int tp = 0; tp < 8; ++tp) {
#pragma unroll
        for (int h = 0; h < 2; ++h) {
            const int t = 2 * tp + h;
            if (t < 15) {             // prefetch tile t+1 (hides under S-MFMA)
                const f16* bh = Bh_p + (size_t)(t + 1) * 6144;
                const f16* bl = Bl_p + (size_t)(t + 1) * 6144;
                const int kn = kb + (t + 1) * 64;
#pragma unroll
                for (int cc = 0; cc < 3; ++cc) {
                    Bch[h ^ 1][cc] = *(const f16x8*)(bh + cc * 32);
                    Bcl[h ^ 1][cc] = *(const f16x8*)(bl + cc * 32);
                }
                v0 = *(const float4*)(Vt_g + (size_t)vr0 * 2048 + kn + vc8);
                v1 = *(const float4*)(Vt_g + (size_t)(vr0 + 32) * 2048 + kn + vc8);
                v2 = *(const float4*)(Vt_g + (size_t)(vr0 + 64) * 2048 + kn + vc8);
            }
            f32x4 accS[4] = {}, accX[4] = {};
            __builtin_amdgcn_s_setprio(1);
#pragma unroll
            for (int cc = 0; cc < 3; ++cc)
#pragma unroll
                for (int mt = 0; mt < 4; ++mt) {
                    accS[mt] = MFMA16(Afh[mt][cc], Bch[h][cc], accS[mt]);
                    accX[mt] = MFMA16(Afh[mt][cc], Bcl[h][cc], accX[mt]);
                    accX[mt] = MFMA16(Afl[mt][cc], Bch[h][cc], accX[mt]);
                }
            __builtin_amdgcn_s_setprio(0);
#pragma unroll
            for (int mt = 0; mt < 4; ++mt)
#pragma unroll
                for (int r = 0; r < 4; ++r) {
                    float zl = fmaf(ZC1, accS[mt][r], ZC2 * accX[mt][r]);
                    P[h][(16 * mt + 4 * quad + r) * 72 + pwc] =
                        (f16)exp2f(zl + negM[mt][r]);
                }
            __syncthreads();          // the single per-tile barrier
            __builtin_amdgcn_s_setprio(1);
#pragma unroll
            for (int kc = 0; kc < 2; ++kc) {
                f16x8 ap = *(const f16x8*)&P[h][(w * 16 + l15) * 72 +
                                               ((kc * 32 + quad * 8 + prr) & 63)];
#pragma unroll
                for (int nt = 0; nt < 7; ++nt) {   // nt=6: ones rows -> partial L
                    f16x8 bv = *(const f16x8*)&Vt[h][(nt * 16 + l15) * 72 + kc * 32 + quad * 8];
                    accO[nt] = MFMA16(ap, bv, accO[nt]);
                }
            }
            __builtin_amdgcn_s_setprio(0);
            if (t < 15) {             // stage Vt(t+1) into the other buffer
                *(float4*)&Vt[h ^ 1][vr0 * 72 + vc8] = v0;
                *(float4*)&Vt[h ^ 1][(vr0 + 32) * 72 + vc8] = v1;
                *(float4*)&Vt[h ^ 1][(vr0 + 64) * 72 + vc8] = v2;
            }
        }
    }
    // write raw fp32 partials (combined + rope'd in fa)
    float* Op = half ? Ob : Oa;
    float* Lp = half ? Lb : La;
    if (l15 == 0) {
#pragma unroll
        for (int r = 0; r < 4; ++r)
            Lp[head * 2048 + q0 + w * 16 + quad * 4 + r] = accO[6][r];
    }
#pragma unroll
    for (int r = 0; r < 4; ++r) {
        const size_t rb = ((size_t)head * 2048 + q0 + w * 16 + quad * 4 + r) * 96;
#pragma unroll
        for (int nt = 0; nt < 6; ++nt)
            Op[rb + nt * 16 + l15] = accO[nt][r];
    }
}

// ============================================================
// FA: finalize k3a. O=(Oa+Ob)/(La+Lb), rope_o, write w1 (f16);
// also writes Lo = La+Lb for k3b. grid 8192 x 256 (4 rows/block).
// ============================================================
__global__ __launch_bounds__(256) void fa(const float* __restrict__ Oa,
                                          const float* __restrict__ Ob,
                                          const float* __restrict__ La,
                                          const float* __restrict__ Lb,
                                          const float* __restrict__ cosb,
                                          const float* __restrict__ sinb,
                                          float* __restrict__ Lo,
                                          f16* __restrict__ w1f) {
    const int tid = threadIdx.x;
    const int rg = tid >> 6, l = tid & 63;
    const int ridx = blockIdx.x * 4 + rg;                // head*2048 + q
    const int head = ridx >> 11, q = ridx & 2047;
    const float L = La[ridx] + Lb[ridx];
    if (l == 0) Lo[ridx] = L;
    if (l >= 48) return;
    const float invL = 1.0f / L;
    const size_t rb = (size_t)ridx * 96;
    const int b = head >> 3, c = head & 7;
    const int cbi = (b * 2048 + q) * 96 + l;
    const float cc = cosb[cbi], ss = sinb[cbi];
    const float a  = (Oa[rb + l] + Ob[rb + l]) * invL;
    const float b2 = (Oa[rb + l + 48] + Ob[rb + l + 48]) * invL;
    f16* wrow = w1f + (size_t)(b * 2048 + q) * 768 + c * 96;
    wrow[l] = (f16)(a * cc + b2 * ss);
    wrow[l + 48] = (f16)(b2 * cc - a * ss);
}

// ============================================================
// K3b: k-split x2, same pipeline as k3a. S2[q][k]=vr_q.ur_k,
// P2=exp2(zl - max(Moa,Mob)[k]) / Lo[k], partial PV -> Oa/Ob.
// ============================================================
__global__ __launch_bounds__(256, 3) void k3b(const f16* __restrict__ uhp,
                                              const f16* __restrict__ ulp,
                                              const f16* __restrict__ vhp,
                                              const f16* __restrict__ vlp,
                                              const f16* __restrict__ oT,
                                              const float* __restrict__ Moa,
                                              const float* __restrict__ Mob,
                                              const float* __restrict__ Lo,
                                              float* __restrict__ Oa,
                                              float* __restrict__ Ob) {
    __shared__ f16 Ot[2][96 * 72];
    __shared__ f16 P[2][64 * 72];
    const int tid = threadIdx.x, w = tid >> 6, lane = tid & 63;
    const int quad = lane >> 4, l15 = lane & 15;
    const int bid0 = blockIdx.y * 64 + blockIdx.x;
    const int swz  = (bid0 & 7) * 128 + (bid0 >> 3);
    const int q0 = (swz & 31) * 64;
    const int head = (swz >> 5) & 15;
    const int half = swz >> 9;
    const int kb = half * 1024;
    const f16* Ah_g = vhp + (size_t)head * 2048 * 96;   // A = vr
    const f16* Al_g = vlp + (size_t)head * 2048 * 96;
    const f16* Ot_g = oT + (size_t)head * 96 * 2048;

    f16x8 Afh[4][3], Afl[4][3];
#pragma unroll
    for (int mt = 0; mt < 4; ++mt)
#pragma unroll
        for (int cc = 0; cc < 3; ++cc) {
            size_t off = (size_t)(q0 + 16 * mt + l15) * 96 + cc * 32 + quad * 8;
            Afh[mt][cc] = *(const f16x8*)(Ah_g + off);
            Afl[mt][cc] = *(const f16x8*)(Al_g + off);
        }

    const f16* Bh_p = uhp + (size_t)head * 2048 * 96 +
                      (size_t)(kb + w * 16 + l15) * 96 + quad * 8;
    const f16* Bl_p = ulp + (size_t)head * 2048 * 96 +
                      (size_t)(kb + w * 16 + l15) * 96 + quad * 8;
    const int vr0 = tid >> 3, vc8 = (tid & 7) * 8;
    const int pwc = (w * 16 + l15 + 16 * quad) & 63;
    const int prr = 16 * (l15 >> 2);

    f16x8 Bch[2][3], Bcl[2][3];
    float4 v0, v1, v2;
#pragma unroll
    for (int cc = 0; cc < 3; ++cc) {
        Bch[0][cc] = *(const f16x8*)(Bh_p + cc * 32);
        Bcl[0][cc] = *(const f16x8*)(Bl_p + cc * 32);
    }
    v0 = *(const float4*)(Ot_g + (size_t)vr0 * 2048 + kb + vc8);
    v1 = *(const float4*)(Ot_g + (size_t)(vr0 + 32) * 2048 + kb + vc8);
    v2 = *(const float4*)(Ot_g + (size_t)(vr0 + 64) * 2048 + kb + vc8);
    *(float4*)&Ot[0][vr0 * 72 + vc8] = v0;
    *(float4*)&Ot[0][(vr0 + 32) * 72 + vc8] = v1;
    *(float4*)&Ot[0][(vr0 + 64) * 72 + vc8] = v2;

    f32x4 accO[6] = {};

    for (int tp = 0; tp < 8; ++tp) {
#pragma unroll
        for (int h = 0; h < 2; ++h) {
            const int t = 2 * tp + h;
            const int gk = head * 2048 + kb + t * 64 + w * 16 + l15;
            const float negMk = -fmaxf(Moa[gk], Mob[gk]);
            const float invLk = 1.0f / Lo[gk];
            if (t < 15) {
                const f16* bh = Bh_p + (size_t)(t + 1) * 6144;
                const f16* bl = Bl_p + (size_t)(t + 1) * 6144;
                const int kn = kb + (t + 1) * 64;
#pragma unroll
                for (int cc = 0; cc < 3; ++cc) {
                    Bch[h ^ 1][cc] = *(const f16x8*)(bh + cc * 32);
                    Bcl[h ^ 1][cc] = *(const f16x8*)(bl + cc * 32);
                }
                v0 = *(const float4*)(Ot_g + (size_t)vr0 * 2048 + kn + vc8);
                v1 = *(const float4*)(Ot_g + (size_t)(vr0 + 32) * 2048 + kn + vc8);
                v2 = *(const float4*)(Ot_g + (size_t)(vr0 + 64) * 2048 + kn + vc8);
            }
            f32x4 accS[4] = {}, accX[4] = {};
            __builtin_amdgcn_s_setprio(1);
#pragma unroll
            for (int cc = 0; cc < 3; ++cc)
#pragma unroll
                for (int mt = 0; mt < 4; ++mt) {
                    accS[mt] = MFMA16(Afh[mt][cc], Bch[h][cc], accS[mt]);
                    // preserve cross-product order: (u_hi*v_lo) first, then (u_lo*v_hi)
                    accX[mt] = MFMA16(Afl[mt][cc], Bch[h][cc], accX[mt]);   // v_lo * u_hi
                    accX[mt] = MFMA16(Afh[mt][cc], Bcl[h][cc], accX[mt]);   // v_hi * u_lo
                }
            __builtin_amdgcn_s_setprio(0);
#pragma unroll
            for (int mt = 0; mt < 4; ++mt)
#pragma unroll
                for (int r = 0; r < 4; ++r) {
                    float zl = fmaf(ZC1, accS[mt][r], ZC2 * accX[mt][r]);
                    P[h][(16 * mt + 4 * quad + r) * 72 + pwc] =
                        (f16)(exp2f(zl + negMk) * invLk);
                }
            __syncthreads();
            __builtin_amdgcn_s_setprio(1);
#pragma unroll
            for (int kc = 0; kc < 2; ++kc) {
                f16x8 ap = *(const f16x8*)&P[h][(w * 16 + l15) * 72 +
                                               ((kc * 32 + quad * 8 + prr) & 63)];
#pragma unroll
                for (int nt = 0; nt < 6; ++nt) {
                    f16x8 bo = *(const f16x8*)&Ot[h][(nt * 16 + l15) * 72 + kc * 32 + quad * 8];
                    accO[nt] = MFMA16(ap, bo, accO[nt]);
                }
            }
            __builtin_amdgcn_s_setprio(0);
            if (t < 15) {
                *(float4*)&Ot[h ^ 1][vr0 * 72 + vc8] = v0;
                *(float4*)&Ot[h ^ 1][(vr0 + 32) * 72 + vc8] = v1;
                *(float4*)&Ot[h ^ 1][(vr0 + 64) * 72 + vc8] = v2;
            }
        }
    }
    float* Op = half ? Ob : Oa;
#pragma unroll
    for (int r = 0; r < 4; ++r) {
        const size_t rb = ((size_t)head * 2048 + q0 + w * 16 + quad * 4 + r) * 96;
#pragma unroll
        for (int nt = 0; nt < 6; ++nt)
            Op[rb + nt * 16 + l15] = accO[nt][r];
    }
}

// ============================================================
// FB: finalize k3b. O=Oa+Ob, rope, write w2 (f16).
// ============================================================
__global__ __launch_bounds__(256) void fb(const float* __restrict__ Oa,
                                          const float* __restrict__ Ob,
                                          const float* __restrict__ cosb,
                                          const float* __restrict__ sinb,
                                          f16* __restrict__ w2f) {
    const int tid = threadIdx.x;
    const int rg = tid >> 6, l = tid & 63;
    const int ridx = blockIdx.x * 4 + rg;
    const int head = ridx >> 11, q = ridx & 2047;
    if (l >= 48) return;
    const size_t rb = (size_t)ridx * 96;
    const int b = head >> 3, c = head & 7;
    const int cbi = (b * 2048 + q) * 96 + l;
    const float cc = cosb[cbi], ss = sinb[cbi];
    const float a  = Oa[rb + l] + Ob[rb + l];
    const float b2 = Oa[rb + l + 48] + Ob[rb + l + 48];
    f16* wrow = w2f + (size_t)(b * 2048 + q) * 768 + c * 96;
    wrow[l] = (f16)(a * cc - b2 * ss);
    wrow[l + 48] = (f16)(b2 * cc + a * ss);
}

// ============================================================
// K4: G = w1@U + w2@V (fp16 MFMA). + XCD d-panel clustering.
// ============================================================
__global__ __launch_bounds__(256, 2) void k4_final(const f16* __restrict__ w1,
                                                   const f16* __restrict__ w2,
                                                   const float* __restrict__ U,
                                                   const float* __restrict__ V,
                                                   float* __restrict__ outp) {
    __shared__ f16 A1[128 * 56];
    __shared__ f16 A2[128 * 56];
    __shared__ f16 B1[64 * 56];
    __shared__ f16 B2[64 * 56];
    const int tid = threadIdx.x, w = tid >> 6, lane = tid & 63;
    const int quad = lane >> 4, l15 = lane & 15;
    const int id = blockIdx.y * 32 + blockIdx.x;         // 0..383
    const int g  = (id & 7) * 48 + (id >> 3);            // XCD-clustered, bijective
    const int bs0 = (g & 31) * 128;
    const int d0 = (g >> 5) * 64;
    f32x4 acc[2][4] = {};

    for (int ec = 0; ec < 24; ++ec) {
        int e0 = ec * 32;
        __syncthreads();
#pragma unroll
        for (int m = 0; m < 2; ++m) {
            int f = tid + 256 * m;
            int row = f >> 2, q = f & 3;
            *(float4*)&A1[row * 56 + q * 8] =
                *(const float4*)(w1 + (size_t)(bs0 + row) * 768 + e0 + q * 8);
            *(float4*)&A2[row * 56 + q * 8] =
                *(const float4*)(w2 + (size_t)(bs0 + row) * 768 + e0 + q * 8);
        }
#pragma unroll
        for (int m2 = 0; m2 < 2; ++m2) {
            int e_r = (tid >> 4) + 16 * m2;
            int dc = tid & 15;
            float4 fu = *(const float4*)(U + (size_t)(e0 + e_r) * 768 + d0 + dc * 4);
            float4 fv = *(const float4*)(V + (size_t)(e0 + e_r) * 768 + d0 + dc * 4);
            B1[(dc * 4 + 0) * 56 + e_r] = (f16)fu.x;
            B1[(dc * 4 + 1) * 56 + e_r] = (f16)fu.y;
            B1[(dc * 4 + 2) * 56 + e_r] = (f16)fu.z;
            B1[(dc * 4 + 3) * 56 + e_r] = (f16)fu.w;
            B2[(dc * 4 + 0) * 56 + e_r] = (f16)fv.x;
            B2[(dc * 4 + 1) * 56 + e_r] = (f16)fv.y;
            B2[(dc * 4 + 2) * 56 + e_r] = (f16)fv.z;
            B2[(dc * 4 + 3) * 56 + e_r] = (f16)fv.w;
        }
        __syncthreads();
        f16x8 a1f[2], a2f[2];
#pragma unroll
        for (int mt = 0; mt < 2; ++mt) {
            a1f[mt] = *(const f16x8*)&A1[(32 * w + 16 * mt + l15) * 56 + quad * 8];
            a2f[mt] = *(const f16x8*)&A2[(32 * w + 16 * mt + l15) * 56 + quad * 8];
        }
#pragma unroll
        for (int nt = 0; nt < 4; ++nt) {
            f16x8 b1f = *(const f16x8*)&B1[(nt * 16 + l15) * 56 + quad * 8];
            f16x8 b2f = *(const f16x8*)&B2[(nt * 16 + l15) * 56 + quad * 8];
#pragma unroll
            for (int mt = 0; mt < 2; ++mt) {
                acc[mt][nt] = MFMA16(a1f[mt], b1f, acc[mt][nt]);
                acc[mt][nt] = MFMA16(a2f[mt], b2f, acc[mt][nt]);
            }
        }
    }
#pragma unroll
    for (int mt = 0; mt < 2; ++mt)
#pragma unroll
        for (int nt = 0; nt < 4; ++nt)
#pragma unroll
            for (int r = 0; r < 4; ++r) {
                int s = bs0 + 32 * w + 16 * mt + 4 * quad + r;
                int d = d0 + 16 * nt + l15;
                outp[(size_t)s * 768 + d] = acc[mt][nt][r];
            }
}

extern "C" void kernel_launch(void* const* d_in, const int* in_sizes, int n_in,
                              void* d_out, int out_size, void* d_ws, size_t ws_size,
                              hipStream_t stream) {
    const float* qz   = (const float*)d_in[0];
    const float* cosb = (const float*)d_in[1];
    const float* sinb = (const float*)d_in[2];
    const float* U    = (const float*)d_in[3];
    const float* V    = (const float*)d_in[4];
    float* outp = (float*)d_out;

    f16* ws16 = (f16*)d_ws;
    f16* uhp = ws16;
    f16* ulp = ws16 + HN;
    f16* vhp = ws16 + 2 * HN;
    f16* vlp = ws16 + 3 * HN;
    f16* vT  = ws16 + 4 * HN;
    f16* oT  = ws16 + 5 * HN;
    // slots 6-7: qzh/qzl for k1, then fp32 partial-O buffer Ob (HN floats).
    f16* qzh = ws16 + 6 * HN;
    f16* qzl = ws16 + 7 * HN;
    float* Ob = (float*)(ws16 + 6 * HN);
    // per-half stats after slot 8
    float* Moa = (float*)(ws16 + 8 * HN);
    float* Mob = Moa + 32768;
    float* Lo  = Moa + 65536;
    float* La  = Moa + 98304;
    float* Lb  = Moa + 131072;

    // d_out: U/V hi/lo splits for k1, then fp32 partial-O buffer Oa,
    // finally the real output (k4).
    f16* outw = (f16*)d_out;
    f16* Uh = outw;
    f16* Ul = outw + UVN;
    f16* Vh = outw + 2 * UVN;
    f16* Vl = outw + 3 * UVN;
    float* Oa = (float*)d_out;

    // final w1/w2 live in the vT/oT slots (dead after k3a/k3b resp.)
    f16* w1f = vT;
    f16* w2f = oT;

    k0_split<<<dim3(3072), 256, 0, stream>>>(qz, U, V, qzh, qzl, Uh, Ul, Vh, Vl);
    k1_proj<<<dim3(64, 8), 256, 0, stream>>>(qzh, qzl, Uh, Ul, Vh, Vl, cosb, sinb,
                                             uhp, ulp, vhp, vlp, vT, oT);
    k2_stats<<<dim3(128, 16), 256, 0, stream>>>(uhp, ulp, vhp, vlp, Moa, Mob);
    k3a<<<dim3(64, 16), 256, 0, stream>>>(uhp, ulp, vhp, vlp, vT, Moa, Mob,
                                          Oa, Ob, La, Lb);
    fa<<<dim3(8192), 256, 0, stream>>>(Oa, Ob, La, Lb, cosb, sinb, Lo, w1f);
    k3b<<<dim3(64, 16), 256, 0, stream>>>(uhp, ulp, vhp, vlp, oT, Moa, Mob, Lo,
                                          Oa, Ob);
    fb<<<dim3(8192), 256, 0, stream>>>(Oa, Ob, cosb, sinb, w2f);
    k4_final<<<dim3(32, 12), 256, 0, stream>>>(w1f, w2f, U, V, outp);
}

// Round 11
// 371.996 us; speedup vs baseline: 2.4694x; 2.4694x over previous
//
#include <hip/hip_runtime.h>

typedef _Float16 f16;
typedef _Float16 f16x8 __attribute__((ext_vector_type(8)));
typedef _Float16 f16x4 __attribute__((ext_vector_type(4)));
typedef float f32x4 __attribute__((ext_vector_type(4)));

#define MFMA16(A,B,C) __builtin_amdgcn_mfma_f32_16x16x32_f16(A,B,C,0,0,0)
#define INV2048 4.8828125e-4f
#define HN (16ll*2048*96)
#define UVN 589824   // 768*768
// z in log2 domain: zl = log2(e)*768*accS + log2(e)*768/2048*accX
#define ZC1 1107.98979f
#define ZC2 0.54101064f

__device__ __forceinline__ void split_f16(float x, f16& h, f16& l) {
    h = (f16)x;
    l = (f16)((x - (float)h) * 2048.0f);   // lo pre-scaled by 2^11 (avoids fp16 denorm loss)
}

// ============================================================
// K0: split qz, U, V (fp32) into fp16 hi/lo pairs. (unchanged)
// ============================================================
__global__ __launch_bounds__(256) void k0_split(const float* __restrict__ qz,
                                                const float* __restrict__ U,
                                                const float* __restrict__ V,
                                                f16* __restrict__ qzh, f16* __restrict__ qzl,
                                                f16* __restrict__ Uh, f16* __restrict__ Ul,
                                                f16* __restrict__ Vh, f16* __restrict__ Vl) {
    const int i4 = blockIdx.x * 256 + threadIdx.x;   // float4 index
    {
        float4 x = *(const float4*)(qz + (size_t)i4 * 4);
        f16 h0, l0, h1, l1, h2, l2, h3, l3;
        split_f16(x.x, h0, l0); split_f16(x.y, h1, l1);
        split_f16(x.z, h2, l2); split_f16(x.w, h3, l3);
        f16x4 hv = {h0, h1, h2, h3};
        f16x4 lv = {l0, l1, l2, l3};
        *(f16x4*)(qzh + (size_t)i4 * 4) = hv;
        *(f16x4*)(qzl + (size_t)i4 * 4) = lv;
    }
    if (i4 < UVN / 4) {
        float4 x = *(const float4*)(U + (size_t)i4 * 4);
        f16 h0, l0, h1, l1, h2, l2, h3, l3;
        split_f16(x.x, h0, l0); split_f16(x.y, h1, l1);
        split_f16(x.z, h2, l2); split_f16(x.w, h3, l3);
        f16x4 hv = {h0, h1, h2, h3};
        f16x4 lv = {l0, l1, l2, l3};
        *(f16x4*)(Uh + (size_t)i4 * 4) = hv;
        *(f16x4*)(Ul + (size_t)i4 * 4) = lv;
        float4 y = *(const float4*)(V + (size_t)i4 * 4);
        split_f16(y.x, h0, l0); split_f16(y.y, h1, l1);
        split_f16(y.z, h2, l2); split_f16(y.w, h3, l3);
        f16x4 hv2 = {h0, h1, h2, h3};
        f16x4 lv2 = {l0, l1, l2, l3};
        *(f16x4*)(Vh + (size_t)i4 * 4) = hv2;
        *(f16x4*)(Vl + (size_t)i4 * 4) = lv2;
    }
}

// ============================================================
// K1: dual GEMM qz@U^T, qz@V^T via fp16 MFMA 3-product emulation
// + RoPE. + XCD-chunked block swizzle. (unchanged, round-8)
// ============================================================
__global__ __launch_bounds__(256, 2) void k1_proj(const f16* __restrict__ qzh,
                                                  const f16* __restrict__ qzl,
                                                  const f16* __restrict__ Uh,
                                                  const f16* __restrict__ Ul,
                                                  const f16* __restrict__ Vh,
                                                  const f16* __restrict__ Vl,
                                                  const float* __restrict__ cosb,
                                                  const float* __restrict__ sinb,
                                                  f16* __restrict__ uhp, f16* __restrict__ ulp,
                                                  f16* __restrict__ vhp, f16* __restrict__ vlp,
                                                  f16* __restrict__ vT, f16* __restrict__ oT) {
    __shared__ __align__(16) f16 smem[36864];            // 73728 B -> 2 blocks/CU
    f16* sAh  = smem;                                    // [64][72]
    f16* sAl  = smem + 4608;
    f16* sBuh = smem + 9216;                             // [96][72]
    f16* sBul = smem + 9216 + 6912;
    f16* sBvh = smem + 9216 + 2 * 6912;
    f16* sBvl = smem + 9216 + 3 * 6912;

    const int tid = threadIdx.x;
    const int w = tid >> 6, lane = tid & 63;
    const int quad = lane >> 4, l15 = lane & 15;
    const int wr = w >> 1, wc = w & 1;                   // 2x2 wave grid
    const int bid0 = blockIdx.y * 64 + blockIdx.x;
    const int swz  = (bid0 & 7) * 64 + (bid0 >> 3);
    const int bs0 = (swz & 63) * 64;
    const int c = swz >> 6;

    const f16* Ug_h = Uh + (size_t)c * 96 * 768;
    const f16* Ug_l = Ul + (size_t)c * 96 * 768;
    const f16* Vg_h = Vh + (size_t)c * 96 * 768;
    const f16* Vg_l = Vl + (size_t)c * 96 * 768;

    f32x4 aUS[2][3] = {}, aUX[2][3] = {};
    f32x4 aVS[2][3] = {}, aVX[2][3] = {};

    for (int k0 = 0; k0 < 768; k0 += 64) {
        __syncthreads();
#pragma unroll
        for (int m = 0; m < 2; ++m) {
            int f = tid + 256 * m, row = f >> 3, cg = f & 7;
            const size_t go = (size_t)(bs0 + row) * 768 + k0 + cg * 8;
            const int lo = row * 72 + cg * 8;
            *(float4*)&sAh[lo] = *(const float4*)(qzh + go);
            *(float4*)&sAl[lo] = *(const float4*)(qzl + go);
        }
#pragma unroll
        for (int m = 0; m < 3; ++m) {
            int f = tid + 256 * m, row = f >> 3, cg = f & 7;
            const size_t go = (size_t)row * 768 + k0 + cg * 8;
            const int lo = row * 72 + cg * 8;
            *(float4*)&sBuh[lo] = *(const float4*)(Ug_h + go);
            *(float4*)&sBul[lo] = *(const float4*)(Ug_l + go);
            *(float4*)&sBvh[lo] = *(const float4*)(Vg_h + go);
            *(float4*)&sBvl[lo] = *(const float4*)(Vg_l + go);
        }
        __syncthreads();
#pragma unroll
        for (int cc = 0; cc < 2; ++cc) {
            f16x8 ah[2], al[2];
#pragma unroll
            for (int mt = 0; mt < 2; ++mt) {
                const int ar = (32 * wr + 16 * mt + l15) * 72 + cc * 32 + quad * 8;
                ah[mt] = *(const f16x8*)&sAh[ar];
                al[mt] = *(const f16x8*)&sAl[ar];
            }
#pragma unroll
            for (int nt = 0; nt < 3; ++nt) {
                const int br = (48 * wc + 16 * nt + l15) * 72 + cc * 32 + quad * 8;
                f16x8 buh = *(const f16x8*)&sBuh[br];
                f16x8 bul = *(const f16x8*)&sBul[br];
                f16x8 bvh = *(const f16x8*)&sBvh[br];
                f16x8 bvl = *(const f16x8*)&sBvl[br];
#pragma unroll
                for (int mt = 0; mt < 2; ++mt) {
                    aUS[mt][nt] = MFMA16(ah[mt], buh, aUS[mt][nt]);
                    aUX[mt][nt] = MFMA16(ah[mt], bul, aUX[mt][nt]);
                    aUX[mt][nt] = MFMA16(al[mt], buh, aUX[mt][nt]);
                    aVS[mt][nt] = MFMA16(ah[mt], bvh, aVS[mt][nt]);
                    aVX[mt][nt] = MFMA16(ah[mt], bvl, aVX[mt][nt]);
                    aVX[mt][nt] = MFMA16(al[mt], bvh, aVX[mt][nt]);
                }
            }
        }
    }

    __syncthreads();
    float* LU = (float*)smem;          // [64][100] = 25.6 KB
    float* LV = LU + 6400;
#pragma unroll
    for (int mt = 0; mt < 2; ++mt)
#pragma unroll
        for (int nt = 0; nt < 3; ++nt)
#pragma unroll
            for (int r = 0; r < 4; ++r) {
                const int sl = 32 * wr + 16 * mt + 4 * quad + r;
                const int col = 48 * wc + 16 * nt + l15;
                LU[sl * 100 + col] = aUS[mt][nt][r] + aUX[mt][nt][r] * INV2048;
                LV[sl * 100 + col] = aVS[mt][nt][r] + aVX[mt][nt][r] * INV2048;
            }
    __syncthreads();

    const int b = bs0 >> 11;
    const int s0 = bs0 & 2047;
    const int head = b * 8 + c;
    const size_t nb = (size_t)head * 2048 * 96;
    const size_t tb = (size_t)head * 96 * 2048;
    const int ty = tid >> 4, tx = tid & 15;

#pragma unroll
    for (int jj = 0; jj < 3; ++jj) {
        int r = tx + 16 * jj;
        f16 vt1[4], vt2[4], ot1[4], ot2[4];
#pragma unroll
        for (int ii = 0; ii < 4; ++ii) {
            int sl = 4 * ty + ii;
            int s = s0 + sl;
            int cbi = (b * 2048 + s) * 96 + r;
            float cc = cosb[cbi], ss = sinb[cbi];
            size_t rowb = nb + (size_t)s * 96;
            float u1 = LU[sl * 100 + r], u2 = LU[sl * 100 + r + 48];
            float v1 = LV[sl * 100 + r], v2 = LV[sl * 100 + r + 48];
            float ur1 = u1 * cc - u2 * ss, ur2 = u2 * cc + u1 * ss;
            float uo1 = u1 * cc + u2 * ss, uo2 = u2 * cc - u1 * ss;
            float vr1 = v1 * cc - v2 * ss, vr2 = v2 * cc + v1 * ss;
            f16 h, l;
            split_f16(ur1, h, l); uhp[rowb + r] = h;      ulp[rowb + r] = l;
            split_f16(ur2, h, l); uhp[rowb + r + 48] = h; ulp[rowb + r + 48] = l;
            split_f16(vr1, h, l); vhp[rowb + r] = h;      vlp[rowb + r] = l;      vt1[ii] = h;
            split_f16(vr2, h, l); vhp[rowb + r + 48] = h; vlp[rowb + r + 48] = l; vt2[ii] = h;
            ot1[ii] = (f16)uo1; ot2[ii] = (f16)uo2;
        }
        f16x4 pv1 = {vt1[0], vt1[1], vt1[2], vt1[3]};
        f16x4 pv2 = {vt2[0], vt2[1], vt2[2], vt2[3]};
        f16x4 po1 = {ot1[0], ot1[1], ot1[2], ot1[3]};
        f16x4 po2 = {ot2[0], ot2[1], ot2[2], ot2[3]};
        *(f16x4*)&vT[tb + (size_t)r * 2048 + s0 + 4 * ty] = pv1;
        *(f16x4*)&vT[tb + (size_t)(r + 48) * 2048 + s0 + 4 * ty] = pv2;
        *(f16x4*)&oT[tb + (size_t)r * 2048 + s0 + 4 * ty] = po1;
        *(f16x4*)&oT[tb + (size_t)(r + 48) * 2048 + s0 + 4 * ty] = po2;
    }
}

// ============================================================
// K2: row MAX, k-split x2 and q-split x2 (grid 2048).
// launch_bounds (256,2): do NOT constrain the allocator (round-10's
// (256,4) forced an 84-VGPR spill). Partial max -> Moa/Mob.
// ============================================================
__global__ __launch_bounds__(256, 2) void k2_stats(const f16* __restrict__ uhp,
                                                   const f16* __restrict__ ulp,
                                                   const f16* __restrict__ vhp,
                                                   const f16* __restrict__ vlp,
                                                   float* __restrict__ Moa,
                                                   float* __restrict__ Mob) {
    __shared__ float Mbuf[4][32];
    const int tid = threadIdx.x, w = tid >> 6, lane = tid & 63;
    const int quad = lane >> 4, l15 = lane & 15;
    const int bid0 = blockIdx.y * 128 + blockIdx.x;      // 0..2047
    const int swz  = (bid0 & 7) * 256 + (bid0 >> 3);     // XCD-chunked, bijective
    const int q0 = (swz & 63) * 32;
    const int head = (swz >> 6) & 15;
    const int half = swz >> 10;
    const f16* Ah_g = uhp + (size_t)head * 2048 * 96;
    const f16* Al_g = ulp + (size_t)head * 2048 * 96;

    f16x8 Afh[2][3], Afl[2][3];
#pragma unroll
    for (int mt = 0; mt < 2; ++mt)
#pragma unroll
        for (int cc = 0; cc < 3; ++cc) {
            size_t off = (size_t)(q0 + 16 * mt + l15) * 96 + cc * 32 + quad * 8;
            Afh[mt][cc] = *(const f16x8*)(Ah_g + off);
            Afl[mt][cc] = *(const f16x8*)(Al_g + off);
        }

    const f16* Bh_p = vhp + (size_t)head * 2048 * 96 +
                      (size_t)(half * 1024 + w * 16 + l15) * 96 + quad * 8;
    const f16* Bl_p = vlp + (size_t)head * 2048 * 96 +
                      (size_t)(half * 1024 + w * 16 + l15) * 96 + quad * 8;

    f16x8 Bch[2][3], Bcl[2][3];
#pragma unroll
    for (int cc = 0; cc < 3; ++cc) {
        Bch[0][cc] = *(const f16x8*)(Bh_p + cc * 32);
        Bcl[0][cc] = *(const f16x8*)(Bl_p + cc * 32);
    }

    float m_run[2][4];
#pragma unroll
    for (int mt = 0; mt < 2; ++mt)
#pragma unroll
        for (int r = 0; r < 4; ++r) m_run[mt][r] = -3.0e38f;

    for (int tp = 0; tp < 8; ++tp) {
#pragma unroll
        for (int h = 0; h < 2; ++h) {
            const int t = 2 * tp + h;
            if (t < 15) {
                const f16* bh = Bh_p + (size_t)(t + 1) * 6144;
                const f16* bl = Bl_p + (size_t)(t + 1) * 6144;
#pragma unroll
                for (int cc = 0; cc < 3; ++cc) {
                    Bch[h ^ 1][cc] = *(const f16x8*)(bh + cc * 32);
                    Bcl[h ^ 1][cc] = *(const f16x8*)(bl + cc * 32);
                }
            }
            f32x4 accS[2] = {}, accX[2] = {};
            __builtin_amdgcn_s_setprio(1);
#pragma unroll
            for (int cc = 0; cc < 3; ++cc)
#pragma unroll
                for (int mt = 0; mt < 2; ++mt) {
                    accS[mt] = MFMA16(Afh[mt][cc], Bch[h][cc], accS[mt]);
                    accX[mt] = MFMA16(Afh[mt][cc], Bcl[h][cc], accX[mt]);
                    accX[mt] = MFMA16(Afl[mt][cc], Bch[h][cc], accX[mt]);
                }
            __builtin_amdgcn_s_setprio(0);
#pragma unroll
            for (int mt = 0; mt < 2; ++mt)
#pragma unroll
                for (int r = 0; r < 4; ++r) {
                    float zl = fmaf(ZC1, accS[mt][r], ZC2 * accX[mt][r]);
                    m_run[mt][r] = fmaxf(m_run[mt][r], zl);
                }
        }
    }
#pragma unroll
    for (int mt = 0; mt < 2; ++mt)
#pragma unroll
        for (int r = 0; r < 4; ++r) {
            float m = m_run[mt][r];
            m = fmaxf(m, __shfl_xor(m, 1)); m = fmaxf(m, __shfl_xor(m, 2));
            m = fmaxf(m, __shfl_xor(m, 4)); m = fmaxf(m, __shfl_xor(m, 8));
            m_run[mt][r] = m;
        }
    if (l15 == 0) {
#pragma unroll
        for (int mt = 0; mt < 2; ++mt)
#pragma unroll
            for (int r = 0; r < 4; ++r)
                Mbuf[w][16 * mt + 4 * quad + r] = m_run[mt][r];
    }
    __syncthreads();
    if (tid < 32) {
        float M = -3.0e38f;
#pragma unroll
        for (int ww = 0; ww < 4; ++ww) M = fmaxf(M, Mbuf[ww][tid]);
        float* Mo_h = half ? Mob : Moa;
        Mo_h[head * 2048 + q0 + tid] = M;    // per-half partial max
    }
}

// ============================================================
// K3a: k-split x2 (grid 1024, 16 k-tiles/block), q-tile 64.
// launch_bounds (256,2): allocator free (~128 VGPR, round-8 proven);
// residency LDS-capped at 3 blocks/CU. S=ur.vr^T,
// P=exp2(zl - max(Moa,Mob)), partial PV (+ones column -> partial L)
// -> raw fp32 Oa/Ob, La/Lb; finalize in fa.
// ============================================================
__global__ __launch_bounds__(256, 2) void k3a(const f16* __restrict__ uhp,
                                              const f16* __restrict__ ulp,
                                              const f16* __restrict__ vhp,
                                              const f16* __restrict__ vlp,
                                              const f16* __restrict__ vT,
                                              const float* __restrict__ Moa,
                                              const float* __restrict__ Mob,
                                              float* __restrict__ Oa,
                                              float* __restrict__ Ob,
                                              float* __restrict__ La,
                                              float* __restrict__ Lb) {
    __shared__ f16 Vt[2][112 * 72];    // rows 96..111 = ones (row-sum block)
    __shared__ f16 P[2][64 * 72];
    const int tid = threadIdx.x, w = tid >> 6, lane = tid & 63;
    const int quad = lane >> 4, l15 = lane & 15;
    const int bid0 = blockIdx.y * 64 + blockIdx.x;       // 0..1023
    const int swz  = (bid0 & 7) * 128 + (bid0 >> 3);     // XCD-chunked, bijective
    const int q0 = (swz & 31) * 64;
    const int head = (swz >> 5) & 15;
    const int half = swz >> 9;
    const int kb = half * 1024;                          // k-row base
    const f16* Ah_g = uhp + (size_t)head * 2048 * 96;
    const f16* Al_g = ulp + (size_t)head * 2048 * 96;
    const f16* Vt_g = vT + (size_t)head * 96 * 2048;

    f16x8 Afh[4][3], Afl[4][3];
#pragma unroll
    for (int mt = 0; mt < 4; ++mt)
#pragma unroll
        for (int cc = 0; cc < 3; ++cc) {
            size_t off = (size_t)(q0 + 16 * mt + l15) * 96 + cc * 32 + quad * 8;
            Afh[mt][cc] = *(const f16x8*)(Ah_g + off);
            Afl[mt][cc] = *(const f16x8*)(Al_g + off);
        }
    float negM[4][4];
#pragma unroll
    for (int mt = 0; mt < 4; ++mt)
#pragma unroll
        for (int r = 0; r < 4; ++r) {
            int i = head * 2048 + q0 + 16 * mt + 4 * quad + r;
            negM[mt][r] = -fmaxf(Moa[i], Mob[i]);
        }

    const f16* Bh_p = vhp + (size_t)head * 2048 * 96 +
                      (size_t)(kb + w * 16 + l15) * 96 + quad * 8;
    const f16* Bl_p = vlp + (size_t)head * 2048 * 96 +
                      (size_t)(kb + w * 16 + l15) * 96 + quad * 8;
    const int vr0 = tid >> 3, vc8 = (tid & 7) * 8;       // Vt rows vr0,+32,+64
    const int pwc = (w * 16 + l15 + 16 * quad) & 63;     // P write col (rotated)
    const int prr = 16 * (l15 >> 2);                     // P read rotation

    if (tid < 144) {
        f16x8 ones = {(f16)1, (f16)1, (f16)1, (f16)1,
                      (f16)1, (f16)1, (f16)1, (f16)1};
        *(f16x8*)&Vt[0][96 * 72 + tid * 8] = ones;
        *(f16x8*)&Vt[1][96 * 72 + tid * 8] = ones;
    }

    f16x8 Bch[2][3], Bcl[2][3];
    float4 v0, v1, v2;
#pragma unroll
    for (int cc = 0; cc < 3; ++cc) {
        Bch[0][cc] = *(const f16x8*)(Bh_p + cc * 32);
        Bcl[0][cc] = *(const f16x8*)(Bl_p + cc * 32);
    }
    v0 = *(const float4*)(Vt_g + (size_t)vr0 * 2048 + kb + vc8);
    v1 = *(const float4*)(Vt_g + (size_t)(vr0 + 32) * 2048 + kb + vc8);
    v2 = *(const float4*)(Vt_g + (size_t)(vr0 + 64) * 2048 + kb + vc8);
    *(float4*)&Vt[0][vr0 * 72 + vc8] = v0;
    *(float4*)&Vt[0][(vr0 + 32) * 72 + vc8] = v1;
    *(float4*)&Vt[0][(vr0 + 64) * 72 + vc8] = v2;

    f32x4 accO[7] = {};

    for (int tp = 0; tp < 8; ++tp) {
#pragma unroll
        for (int h = 0; h < 2; ++h) {
            const int t = 2 * tp + h;
            if (t < 15) {             // prefetch tile t+1 (hides under S-MFMA)
                const f16* bh = Bh_p + (size_t)(t + 1) * 6144;
                const f16* bl = Bl_p + (size_t)(t + 1) * 6144;
                const int kn = kb + (t + 1) * 64;
#pragma unroll
                for (int cc = 0; cc < 3; ++cc) {
                    Bch[h ^ 1][cc] = *(const f16x8*)(bh + cc * 32);
                    Bcl[h ^ 1][cc] = *(const f16x8*)(bl + cc * 32);
                }
                v0 = *(const float4*)(Vt_g + (size_t)vr0 * 2048 + kn + vc8);
                v1 = *(const float4*)(Vt_g + (size_t)(vr0 + 32) * 2048 + kn + vc8);
                v2 = *(const float4*)(Vt_g + (size_t)(vr0 + 64) * 2048 + kn + vc8);
            }
            f32x4 accS[4] = {}, accX[4] = {};
            __builtin_amdgcn_s_setprio(1);
#pragma unroll
            for (int cc = 0; cc < 3; ++cc)
#pragma unroll
                for (int mt = 0; mt < 4; ++mt) {
                    accS[mt] = MFMA16(Afh[mt][cc], Bch[h][cc], accS[mt]);
                    accX[mt] = MFMA16(Afh[mt][cc], Bcl[h][cc], accX[mt]);
                    accX[mt] = MFMA16(Afl[mt][cc], Bch[h][cc], accX[mt]);
                }
            __builtin_amdgcn_s_setprio(0);
#pragma unroll
            for (int mt = 0; mt < 4; ++mt)
#pragma unroll
                for (int r = 0; r < 4; ++r) {
                    float zl = fmaf(ZC1, accS[mt][r], ZC2 * accX[mt][r]);
                    P[h][(16 * mt + 4 * quad + r) * 72 + pwc] =
                        (f16)exp2f(zl + negM[mt][r]);
                }
            __syncthreads();          // the single per-tile barrier
            __builtin_amdgcn_s_setprio(1);
#pragma unroll
            for (int kc = 0; kc < 2; ++kc) {
                f16x8 ap = *(const f16x8*)&P[h][(w * 16 + l15) * 72 +
                                               ((kc * 32 + quad * 8 + prr) & 63)];
#pragma unroll
                for (int nt = 0; nt < 7; ++nt) {   // nt=6: ones rows -> partial L
                    f16x8 bv = *(const f16x8*)&Vt[h][(nt * 16 + l15) * 72 + kc * 32 + quad * 8];
                    accO[nt] = MFMA16(ap, bv, accO[nt]);
                }
            }
            __builtin_amdgcn_s_setprio(0);
            if (t < 15) {             // stage Vt(t+1) into the other buffer
                *(float4*)&Vt[h ^ 1][vr0 * 72 + vc8] = v0;
                *(float4*)&Vt[h ^ 1][(vr0 + 32) * 72 + vc8] = v1;
                *(float4*)&Vt[h ^ 1][(vr0 + 64) * 72 + vc8] = v2;
            }
        }
    }
    // write raw fp32 partials (combined + rope'd in fa)
    float* Op = half ? Ob : Oa;
    float* Lp = half ? Lb : La;
    if (l15 == 0) {
#pragma unroll
        for (int r = 0; r < 4; ++r)
            Lp[head * 2048 + q0 + w * 16 + quad * 4 + r] = accO[6][r];
    }
#pragma unroll
    for (int r = 0; r < 4; ++r) {
        const size_t rb = ((size_t)head * 2048 + q0 + w * 16 + quad * 4 + r) * 96;
#pragma unroll
        for (int nt = 0; nt < 6; ++nt)
            Op[rb + nt * 16 + l15] = accO[nt][r];
    }
}

// ============================================================
// FA: finalize k3a. O=(Oa+Ob)/(La+Lb), rope_o, write w1 (f16);
// also writes Lo = La+Lb for k3b. grid 8192 x 256 (4 rows/block).
// ============================================================
__global__ __launch_bounds__(256) void fa(const float* __restrict__ Oa,
                                          const float* __restrict__ Ob,
                                          const float* __restrict__ La,
                                          const float* __restrict__ Lb,
                                          const float* __restrict__ cosb,
                                          const float* __restrict__ sinb,
                                          float* __restrict__ Lo,
                                          f16* __restrict__ w1f) {
    const int tid = threadIdx.x;
    const int rg = tid >> 6, l = tid & 63;
    const int ridx = blockIdx.x * 4 + rg;                // head*2048 + q
    const int head = ridx >> 11, q = ridx & 2047;
    const float L = La[ridx] + Lb[ridx];
    if (l == 0) Lo[ridx] = L;
    if (l >= 48) return;
    const float invL = 1.0f / L;
    const size_t rb = (size_t)ridx * 96;
    const int b = head >> 3, c = head & 7;
    const int cbi = (b * 2048 + q) * 96 + l;
    const float cc = cosb[cbi], ss = sinb[cbi];
    const float a  = (Oa[rb + l] + Ob[rb + l]) * invL;
    const float b2 = (Oa[rb + l + 48] + Ob[rb + l + 48]) * invL;
    f16* wrow = w1f + (size_t)(b * 2048 + q) * 768 + c * 96;
    wrow[l] = (f16)(a * cc + b2 * ss);
    wrow[l + 48] = (f16)(b2 * cc - a * ss);
}

// ============================================================
// K3b: k-split x2, same pipeline as k3a. S2[q][k]=vr_q.ur_k,
// P2=exp2(zl - max(Moa,Mob)[k]) / Lo[k], partial PV -> Oa/Ob.
// ============================================================
__global__ __launch_bounds__(256, 2) void k3b(const f16* __restrict__ uhp,
                                              const f16* __restrict__ ulp,
                                              const f16* __restrict__ vhp,
                                              const f16* __restrict__ vlp,
                                              const f16* __restrict__ oT,
                                              const float* __restrict__ Moa,
                                              const float* __restrict__ Mob,
                                              const float* __restrict__ Lo,
                                              float* __restrict__ Oa,
                                              float* __restrict__ Ob) {
    __shared__ f16 Ot[2][96 * 72];
    __shared__ f16 P[2][64 * 72];
    const int tid = threadIdx.x, w = tid >> 6, lane = tid & 63;
    const int quad = lane >> 4, l15 = lane & 15;
    const int bid0 = blockIdx.y * 64 + blockIdx.x;
    const int swz  = (bid0 & 7) * 128 + (bid0 >> 3);
    const int q0 = (swz & 31) * 64;
    const int head = (swz >> 5) & 15;
    const int half = swz >> 9;
    const int kb = half * 1024;
    const f16* Ah_g = vhp + (size_t)head * 2048 * 96;   // A = vr
    const f16* Al_g = vlp + (size_t)head * 2048 * 96;
    const f16* Ot_g = oT + (size_t)head * 96 * 2048;

    f16x8 Afh[4][3], Afl[4][3];
#pragma unroll
    for (int mt = 0; mt < 4; ++mt)
#pragma unroll
        for (int cc = 0; cc < 3; ++cc) {
            size_t off = (size_t)(q0 + 16 * mt + l15) * 96 + cc * 32 + quad * 8;
            Afh[mt][cc] = *(const f16x8*)(Ah_g + off);
            Afl[mt][cc] = *(const f16x8*)(Al_g + off);
        }

    const f16* Bh_p = uhp + (size_t)head * 2048 * 96 +
                      (size_t)(kb + w * 16 + l15) * 96 + quad * 8;
    const f16* Bl_p = ulp + (size_t)head * 2048 * 96 +
                      (size_t)(kb + w * 16 + l15) * 96 + quad * 8;
    const int vr0 = tid >> 3, vc8 = (tid & 7) * 8;
    const int pwc = (w * 16 + l15 + 16 * quad) & 63;
    const int prr = 16 * (l15 >> 2);

    f16x8 Bch[2][3], Bcl[2][3];
    float4 v0, v1, v2;
#pragma unroll
    for (int cc = 0; cc < 3; ++cc) {
        Bch[0][cc] = *(const f16x8*)(Bh_p + cc * 32);
        Bcl[0][cc] = *(const f16x8*)(Bl_p + cc * 32);
    }
    v0 = *(const float4*)(Ot_g + (size_t)vr0 * 2048 + kb + vc8);
    v1 = *(const float4*)(Ot_g + (size_t)(vr0 + 32) * 2048 + kb + vc8);
    v2 = *(const float4*)(Ot_g + (size_t)(vr0 + 64) * 2048 + kb + vc8);
    *(float4*)&Ot[0][vr0 * 72 + vc8] = v0;
    *(float4*)&Ot[0][(vr0 + 32) * 72 + vc8] = v1;
    *(float4*)&Ot[0][(vr0 + 64) * 72 + vc8] = v2;

    f32x4 accO[6] = {};

    for (int tp = 0; tp < 8; ++tp) {
#pragma unroll
        for (int h = 0; h < 2; ++h) {
            const int t = 2 * tp + h;
            const int gk = head * 2048 + kb + t * 64 + w * 16 + l15;
            const float negMk = -fmaxf(Moa[gk], Mob[gk]);
            const float invLk = 1.0f / Lo[gk];
            if (t < 15) {
                const f16* bh = Bh_p + (size_t)(t + 1) * 6144;
                const f16* bl = Bl_p + (size_t)(t + 1) * 6144;
                const int kn = kb + (t + 1) * 64;
#pragma unroll
                for (int cc = 0; cc < 3; ++cc) {
                    Bch[h ^ 1][cc] = *(const f16x8*)(bh + cc * 32);
                    Bcl[h ^ 1][cc] = *(const f16x8*)(bl + cc * 32);
                }
                v0 = *(const float4*)(Ot_g + (size_t)vr0 * 2048 + kn + vc8);
                v1 = *(const float4*)(Ot_g + (size_t)(vr0 + 32) * 2048 + kn + vc8);
                v2 = *(const float4*)(Ot_g + (size_t)(vr0 + 64) * 2048 + kn + vc8);
            }
            f32x4 accS[4] = {}, accX[4] = {};
            __builtin_amdgcn_s_setprio(1);
#pragma unroll
            for (int cc = 0; cc < 3; ++cc)
#pragma unroll
                for (int mt = 0; mt < 4; ++mt) {
                    accS[mt] = MFMA16(Afh[mt][cc], Bch[h][cc], accS[mt]);
                    // preserve cross-product order: (u_hi*v_lo) first, then (u_lo*v_hi)
                    accX[mt] = MFMA16(Afl[mt][cc], Bch[h][cc], accX[mt]);   // v_lo * u_hi
                    accX[mt] = MFMA16(Afh[mt][cc], Bcl[h][cc], accX[mt]);   // v_hi * u_lo
                }
            __builtin_amdgcn_s_setprio(0);
#pragma unroll
            for (int mt = 0; mt < 4; ++mt)
#pragma unroll
                for (int r = 0; r < 4; ++r) {
                    float zl = fmaf(ZC1, accS[mt][r], ZC2 * accX[mt][r]);
                    P[h][(16 * mt + 4 * quad + r) * 72 + pwc] =
                        (f16)(exp2f(zl + negMk) * invLk);
                }
            __syncthreads();
            __builtin_amdgcn_s_setprio(1);
#pragma unroll
            for (int kc = 0; kc < 2; ++kc) {
                f16x8 ap = *(const f16x8*)&P[h][(w * 16 + l15) * 72 +
                                               ((kc * 32 + quad * 8 + prr) & 63)];
#pragma unroll
                for (int nt = 0; nt < 6; ++nt) {
                    f16x8 bo = *(const f16x8*)&Ot[h][(nt * 16 + l15) * 72 + kc * 32 + quad * 8];
                    accO[nt] = MFMA16(ap, bo, accO[nt]);
                }
            }
            __builtin_amdgcn_s_setprio(0);
            if (t < 15) {
                *(float4*)&Ot[h ^ 1][vr0 * 72 + vc8] = v0;
                *(float4*)&Ot[h ^ 1][(vr0 + 32) * 72 + vc8] = v1;
                *(float4*)&Ot[h ^ 1][(vr0 + 64) * 72 + vc8] = v2;
            }
        }
    }
    float* Op = half ? Ob : Oa;
#pragma unroll
    for (int r = 0; r < 4; ++r) {
        const size_t rb = ((size_t)head * 2048 + q0 + w * 16 + quad * 4 + r) * 96;
#pragma unroll
        for (int nt = 0; nt < 6; ++nt)
            Op[rb + nt * 16 + l15] = accO[nt][r];
    }
}

// ============================================================
// FB: finalize k3b. O=Oa+Ob, rope, write w2 (f16).
// ============================================================
__global__ __launch_bounds__(256) void fb(const float* __restrict__ Oa,
                                          const float* __restrict__ Ob,
                                          const float* __restrict__ cosb,
                                          const float* __restrict__ sinb,
                                          f16* __restrict__ w2f) {
    const int tid = threadIdx.x;
    const int rg = tid >> 6, l = tid & 63;
    const int ridx = blockIdx.x * 4 + rg;
    const int head = ridx >> 11, q = ridx & 2047;
    if (l >= 48) return;
    const size_t rb = (size_t)ridx * 96;
    const int b = head >> 3, c = head & 7;
    const int cbi = (b * 2048 + q) * 96 + l;
    const float cc = cosb[cbi], ss = sinb[cbi];
    const float a  = Oa[rb + l] + Ob[rb + l];
    const float b2 = Oa[rb + l + 48] + Ob[rb + l + 48];
    f16* wrow = w2f + (size_t)(b * 2048 + q) * 768 + c * 96;
    wrow[l] = (f16)(a * cc - b2 * ss);
    wrow[l + 48] = (f16)(b2 * cc + a * ss);
}

// ============================================================
// K4: G = w1@U + w2@V (fp16 MFMA). + XCD d-panel clustering.
// ============================================================
__global__ __launch_bounds__(256, 2) void k4_final(const f16* __restrict__ w1,
                                                   const f16* __restrict__ w2,
                                                   const float* __restrict__ U,
                                                   const float* __restrict__ V,
                                                   float* __restrict__ outp) {
    __shared__ f16 A1[128 * 56];
    __shared__ f16 A2[128 * 56];
    __shared__ f16 B1[64 * 56];
    __shared__ f16 B2[64 * 56];
    const int tid = threadIdx.x, w = tid >> 6, lane = tid & 63;
    const int quad = lane >> 4, l15 = lane & 15;
    const int id = blockIdx.y * 32 + blockIdx.x;         // 0..383
    const int g  = (id & 7) * 48 + (id >> 3);            // XCD-clustered, bijective
    const int bs0 = (g & 31) * 128;
    const int d0 = (g >> 5) * 64;
    f32x4 acc[2][4] = {};

    for (int ec = 0; ec < 24; ++ec) {
        int e0 = ec * 32;
        __syncthreads();
#pragma unroll
        for (int m = 0; m < 2; ++m) {
            int f = tid + 256 * m;
            int row = f >> 2, q = f & 3;
            *(float4*)&A1[row * 56 + q * 8] =
                *(const float4*)(w1 + (size_t)(bs0 + row) * 768 + e0 + q * 8);
            *(float4*)&A2[row * 56 + q * 8] =
                *(const float4*)(w2 + (size_t)(bs0 + row) * 768 + e0 + q * 8);
        }
#pragma unroll
        for (int m2 = 0; m2 < 2; ++m2) {
            int e_r = (tid >> 4) + 16 * m2;
            int dc = tid & 15;
            float4 fu = *(const float4*)(U + (size_t)(e0 + e_r) * 768 + d0 + dc * 4);
            float4 fv = *(const float4*)(V + (size_t)(e0 + e_r) * 768 + d0 + dc * 4);
            B1[(dc * 4 + 0) * 56 + e_r] = (f16)fu.x;
            B1[(dc * 4 + 1) * 56 + e_r] = (f16)fu.y;
            B1[(dc * 4 + 2) * 56 + e_r] = (f16)fu.z;
            B1[(dc * 4 + 3) * 56 + e_r] = (f16)fu.w;
            B2[(dc * 4 + 0) * 56 + e_r] = (f16)fv.x;
            B2[(dc * 4 + 1) * 56 + e_r] = (f16)fv.y;
            B2[(dc * 4 + 2) * 56 + e_r] = (f16)fv.z;
            B2[(dc * 4 + 3) * 56 + e_r] = (f16)fv.w;
        }
        __syncthreads();
        f16x8 a1f[2], a2f[2];
#pragma unroll
        for (int mt = 0; mt < 2; ++mt) {
            a1f[mt] = *(const f16x8*)&A1[(32 * w + 16 * mt + l15) * 56 + quad * 8];
            a2f[mt] = *(const f16x8*)&A2[(32 * w + 16 * mt + l15) * 56 + quad * 8];
        }
#pragma unroll
        for (int nt = 0; nt < 4; ++nt) {
            f16x8 b1f = *(const f16x8*)&B1[(nt * 16 + l15) * 56 + quad * 8];
            f16x8 b2f = *(const f16x8*)&B2[(nt * 16 + l15) * 56 + quad * 8];
#pragma unroll
            for (int mt = 0; mt < 2; ++mt) {
                acc[mt][nt] = MFMA16(a1f[mt], b1f, acc[mt][nt]);
                acc[mt][nt] = MFMA16(a2f[mt], b2f, acc[mt][nt]);
            }
        }
    }
#pragma unroll
    for (int mt = 0; mt < 2; ++mt)
#pragma unroll
        for (int nt = 0; nt < 4; ++nt)
#pragma unroll
            for (int r = 0; r < 4; ++r) {
                int s = bs0 + 32 * w + 16 * mt + 4 * quad + r;
                int d = d0 + 16 * nt + l15;
                outp[(size_t)s * 768 + d] = acc[mt][nt][r];
            }
}

extern "C" void kernel_launch(void* const* d_in, const int* in_sizes, int n_in,
                              void* d_out, int out_size, void* d_ws, size_t ws_size,
                              hipStream_t stream) {
    const float* qz   = (const float*)d_in[0];
    const float* cosb = (const float*)d_in[1];
    const float* sinb = (const float*)d_in[2];
    const float* U    = (const float*)d_in[3];
    const float* V    = (const float*)d_in[4];
    float* outp = (float*)d_out;

    f16* ws16 = (f16*)d_ws;
    f16* uhp = ws16;
    f16* ulp = ws16 + HN;
    f16* vhp = ws16 + 2 * HN;
    f16* vlp = ws16 + 3 * HN;
    f16* vT  = ws16 + 4 * HN;
    f16* oT  = ws16 + 5 * HN;
    // slots 6-7: qzh/qzl for k1, then fp32 partial-O buffer Ob (HN floats).
    f16* qzh = ws16 + 6 * HN;
    f16* qzl = ws16 + 7 * HN;
    float* Ob = (float*)(ws16 + 6 * HN);
    // per-half stats after slot 8
    float* Moa = (float*)(ws16 + 8 * HN);
    float* Mob = Moa + 32768;
    float* Lo  = Moa + 65536;
    float* La  = Moa + 98304;
    float* Lb  = Moa + 131072;

    // d_out: U/V hi/lo splits for k1, then fp32 partial-O buffer Oa,
    // finally the real output (k4).
    f16* outw = (f16*)d_out;
    f16* Uh = outw;
    f16* Ul = outw + UVN;
    f16* Vh = outw + 2 * UVN;
    f16* Vl = outw + 3 * UVN;
    float* Oa = (float*)d_out;

    // final w1/w2 live in the vT/oT slots (dead after k3a/k3b resp.)
    f16* w1f = vT;
    f16* w2f = oT;

    k0_split<<<dim3(3072), 256, 0, stream>>>(qz, U, V, qzh, qzl, Uh, Ul, Vh, Vl);
    k1_proj<<<dim3(64, 8), 256, 0, stream>>>(qzh, qzl, Uh, Ul, Vh, Vl, cosb, sinb,
                                             uhp, ulp, vhp, vlp, vT, oT);
    k2_stats<<<dim3(128, 16), 256, 0, stream>>>(uhp, ulp, vhp, vlp, Moa, Mob);
    k3a<<<dim3(64, 16), 256, 0, stream>>>(uhp, ulp, vhp, vlp, vT, Moa, Mob,
                                          Oa, Ob, La, Lb);
    fa<<<dim3(8192), 256, 0, stream>>>(Oa, Ob, La, Lb, cosb, sinb, Lo, w1f);
    k3b<<<dim3(64, 16), 256, 0, stream>>>(uhp, ulp, vhp, vlp, oT, Moa, Mob, Lo,
                                          Oa, Ob);
    fb<<<dim3(8192), 256, 0, stream>>>(Oa, Ob, cosb, sinb, w2f);
    k4_final<<<dim3(32, 12), 256, 0, stream>>>(w1f, w2f, U, V, outp);
}

// Round 12
// 337.539 us; speedup vs baseline: 2.7215x; 1.1021x over previous
//
#include <hip/hip_runtime.h>

typedef _Float16 f16;
typedef _Float16 f16x8 __attribute__((ext_vector_type(8)));
typedef _Float16 f16x4 __attribute__((ext_vector_type(4)));
typedef float f32x4 __attribute__((ext_vector_type(4)));

#define MFMA16(A,B,C) __builtin_amdgcn_mfma_f32_16x16x32_f16(A,B,C,0,0,0)
#define INV2048 4.8828125e-4f
#define HN (16ll*2048*96)
#define UVN 589824   // 768*768
// z in log2 domain: zl = log2(e)*768*accS + log2(e)*768/2048*accX
#define ZC1 1107.98979f
#define ZC2 0.54101064f

__device__ __forceinline__ void split_f16(float x, f16& h, f16& l) {
    h = (f16)x;
    l = (f16)((x - (float)h) * 2048.0f);   // lo pre-scaled by 2^11 (avoids fp16 denorm loss)
}

// ============================================================
// K0: split qz, U, V (fp32) into fp16 hi/lo pairs.
// ============================================================
__global__ __launch_bounds__(256) void k0_split(const float* __restrict__ qz,
                                                const float* __restrict__ U,
                                                const float* __restrict__ V,
                                                f16* __restrict__ qzh, f16* __restrict__ qzl,
                                                f16* __restrict__ Uh, f16* __restrict__ Ul,
                                                f16* __restrict__ Vh, f16* __restrict__ Vl) {
    const int i4 = blockIdx.x * 256 + threadIdx.x;   // float4 index
    {
        float4 x = *(const float4*)(qz + (size_t)i4 * 4);
        f16 h0, l0, h1, l1, h2, l2, h3, l3;
        split_f16(x.x, h0, l0); split_f16(x.y, h1, l1);
        split_f16(x.z, h2, l2); split_f16(x.w, h3, l3);
        f16x4 hv = {h0, h1, h2, h3};
        f16x4 lv = {l0, l1, l2, l3};
        *(f16x4*)(qzh + (size_t)i4 * 4) = hv;
        *(f16x4*)(qzl + (size_t)i4 * 4) = lv;
    }
    if (i4 < UVN / 4) {
        float4 x = *(const float4*)(U + (size_t)i4 * 4);
        f16 h0, l0, h1, l1, h2, l2, h3, l3;
        split_f16(x.x, h0, l0); split_f16(x.y, h1, l1);
        split_f16(x.z, h2, l2); split_f16(x.w, h3, l3);
        f16x4 hv = {h0, h1, h2, h3};
        f16x4 lv = {l0, l1, l2, l3};
        *(f16x4*)(Uh + (size_t)i4 * 4) = hv;
        *(f16x4*)(Ul + (size_t)i4 * 4) = lv;
        float4 y = *(const float4*)(V + (size_t)i4 * 4);
        split_f16(y.x, h0, l0); split_f16(y.y, h1, l1);
        split_f16(y.z, h2, l2); split_f16(y.w, h3, l3);
        f16x4 hv2 = {h0, h1, h2, h3};
        f16x4 lv2 = {l0, l1, l2, l3};
        *(f16x4*)(Vh + (size_t)i4 * 4) = hv2;
        *(f16x4*)(Vl + (size_t)i4 * 4) = lv2;
    }
}

// ============================================================
// K1: dual GEMM qz@U^T, qz@V^T via fp16 MFMA 3-product emulation
// + RoPE. + XCD-chunked block swizzle. (round-8 proven)
// ============================================================
__global__ __launch_bounds__(256, 2) void k1_proj(const f16* __restrict__ qzh,
                                                  const f16* __restrict__ qzl,
                                                  const f16* __restrict__ Uh,
                                                  const f16* __restrict__ Ul,
                                                  const f16* __restrict__ Vh,
                                                  const f16* __restrict__ Vl,
                                                  const float* __restrict__ cosb,
                                                  const float* __restrict__ sinb,
                                                  f16* __restrict__ uhp, f16* __restrict__ ulp,
                                                  f16* __restrict__ vhp, f16* __restrict__ vlp,
                                                  f16* __restrict__ vT, f16* __restrict__ oT) {
    __shared__ __align__(16) f16 smem[36864];            // 73728 B -> 2 blocks/CU
    f16* sAh  = smem;                                    // [64][72]
    f16* sAl  = smem + 4608;
    f16* sBuh = smem + 9216;                             // [96][72]
    f16* sBul = smem + 9216 + 6912;
    f16* sBvh = smem + 9216 + 2 * 6912;
    f16* sBvl = smem + 9216 + 3 * 6912;

    const int tid = threadIdx.x;
    const int w = tid >> 6, lane = tid & 63;
    const int quad = lane >> 4, l15 = lane & 15;
    const int wr = w >> 1, wc = w & 1;                   // 2x2 wave grid
    const int bid0 = blockIdx.y * 64 + blockIdx.x;
    const int swz  = (bid0 & 7) * 64 + (bid0 >> 3);
    const int bs0 = (swz & 63) * 64;
    const int c = swz >> 6;

    const f16* Ug_h = Uh + (size_t)c * 96 * 768;
    const f16* Ug_l = Ul + (size_t)c * 96 * 768;
    const f16* Vg_h = Vh + (size_t)c * 96 * 768;
    const f16* Vg_l = Vl + (size_t)c * 96 * 768;

    f32x4 aUS[2][3] = {}, aUX[2][3] = {};
    f32x4 aVS[2][3] = {}, aVX[2][3] = {};

    for (int k0 = 0; k0 < 768; k0 += 64) {
        __syncthreads();
#pragma unroll
        for (int m = 0; m < 2; ++m) {
            int f = tid + 256 * m, row = f >> 3, cg = f & 7;
            const size_t go = (size_t)(bs0 + row) * 768 + k0 + cg * 8;
            const int lo = row * 72 + cg * 8;
            *(float4*)&sAh[lo] = *(const float4*)(qzh + go);
            *(float4*)&sAl[lo] = *(const float4*)(qzl + go);
        }
#pragma unroll
        for (int m = 0; m < 3; ++m) {
            int f = tid + 256 * m, row = f >> 3, cg = f & 7;
            const size_t go = (size_t)row * 768 + k0 + cg * 8;
            const int lo = row * 72 + cg * 8;
            *(float4*)&sBuh[lo] = *(const float4*)(Ug_h + go);
            *(float4*)&sBul[lo] = *(const float4*)(Ug_l + go);
            *(float4*)&sBvh[lo] = *(const float4*)(Vg_h + go);
            *(float4*)&sBvl[lo] = *(const float4*)(Vg_l + go);
        }
        __syncthreads();
#pragma unroll
        for (int cc = 0; cc < 2; ++cc) {
            f16x8 ah[2], al[2];
#pragma unroll
            for (int mt = 0; mt < 2; ++mt) {
                const int ar = (32 * wr + 16 * mt + l15) * 72 + cc * 32 + quad * 8;
                ah[mt] = *(const f16x8*)&sAh[ar];
                al[mt] = *(const f16x8*)&sAl[ar];
            }
#pragma unroll
            for (int nt = 0; nt < 3; ++nt) {
                const int br = (48 * wc + 16 * nt + l15) * 72 + cc * 32 + quad * 8;
                f16x8 buh = *(const f16x8*)&sBuh[br];
                f16x8 bul = *(const f16x8*)&sBul[br];
                f16x8 bvh = *(const f16x8*)&sBvh[br];
                f16x8 bvl = *(const f16x8*)&sBvl[br];
#pragma unroll
                for (int mt = 0; mt < 2; ++mt) {
                    aUS[mt][nt] = MFMA16(ah[mt], buh, aUS[mt][nt]);
                    aUX[mt][nt] = MFMA16(ah[mt], bul, aUX[mt][nt]);
                    aUX[mt][nt] = MFMA16(al[mt], buh, aUX[mt][nt]);
                    aVS[mt][nt] = MFMA16(ah[mt], bvh, aVS[mt][nt]);
                    aVX[mt][nt] = MFMA16(ah[mt], bvl, aVX[mt][nt]);
                    aVX[mt][nt] = MFMA16(al[mt], bvh, aVX[mt][nt]);
                }
            }
        }
    }

    __syncthreads();
    float* LU = (float*)smem;          // [64][100] = 25.6 KB
    float* LV = LU + 6400;
#pragma unroll
    for (int mt = 0; mt < 2; ++mt)
#pragma unroll
        for (int nt = 0; nt < 3; ++nt)
#pragma unroll
            for (int r = 0; r < 4; ++r) {
                const int sl = 32 * wr + 16 * mt + 4 * quad + r;
                const int col = 48 * wc + 16 * nt + l15;
                LU[sl * 100 + col] = aUS[mt][nt][r] + aUX[mt][nt][r] * INV2048;
                LV[sl * 100 + col] = aVS[mt][nt][r] + aVX[mt][nt][r] * INV2048;
            }
    __syncthreads();

    const int b = bs0 >> 11;
    const int s0 = bs0 & 2047;
    const int head = b * 8 + c;
    const size_t nb = (size_t)head * 2048 * 96;
    const size_t tb = (size_t)head * 96 * 2048;
    const int ty = tid >> 4, tx = tid & 15;

#pragma unroll
    for (int jj = 0; jj < 3; ++jj) {
        int r = tx + 16 * jj;
        f16 vt1[4], vt2[4], ot1[4], ot2[4];
#pragma unroll
        for (int ii = 0; ii < 4; ++ii) {
            int sl = 4 * ty + ii;
            int s = s0 + sl;
            int cbi = (b * 2048 + s) * 96 + r;
            float cc = cosb[cbi], ss = sinb[cbi];
            size_t rowb = nb + (size_t)s * 96;
            float u1 = LU[sl * 100 + r], u2 = LU[sl * 100 + r + 48];
            float v1 = LV[sl * 100 + r], v2 = LV[sl * 100 + r + 48];
            float ur1 = u1 * cc - u2 * ss, ur2 = u2 * cc + u1 * ss;
            float uo1 = u1 * cc + u2 * ss, uo2 = u2 * cc - u1 * ss;
            float vr1 = v1 * cc - v2 * ss, vr2 = v2 * cc + v1 * ss;
            f16 h, l;
            split_f16(ur1, h, l); uhp[rowb + r] = h;      ulp[rowb + r] = l;
            split_f16(ur2, h, l); uhp[rowb + r + 48] = h; ulp[rowb + r + 48] = l;
            split_f16(vr1, h, l); vhp[rowb + r] = h;      vlp[rowb + r] = l;      vt1[ii] = h;
            split_f16(vr2, h, l); vhp[rowb + r + 48] = h; vlp[rowb + r + 48] = l; vt2[ii] = h;
            ot1[ii] = (f16)uo1; ot2[ii] = (f16)uo2;
        }
        f16x4 pv1 = {vt1[0], vt1[1], vt1[2], vt1[3]};
        f16x4 pv2 = {vt2[0], vt2[1], vt2[2], vt2[3]};
        f16x4 po1 = {ot1[0], ot1[1], ot1[2], ot1[3]};
        f16x4 po2 = {ot2[0], ot2[1], ot2[2], ot2[3]};
        *(f16x4*)&vT[tb + (size_t)r * 2048 + s0 + 4 * ty] = pv1;
        *(f16x4*)&vT[tb + (size_t)(r + 48) * 2048 + s0 + 4 * ty] = pv2;
        *(f16x4*)&oT[tb + (size_t)r * 2048 + s0 + 4 * ty] = po1;
        *(f16x4*)&oT[tb + (size_t)(r + 48) * 2048 + s0 + 4 * ty] = po2;
    }
}

// ============================================================
// K2: MFMA row MAX only. Direct global B-frags (each (k,col) owned
// by exactly one lane), 1-tile-ahead prefetch, no LDS/barriers in
// loop. (round-8 proven)
// ============================================================
__global__ __launch_bounds__(256, 2) void k2_stats(const f16* __restrict__ uhp,
                                                   const f16* __restrict__ ulp,
                                                   const f16* __restrict__ vhp,
                                                   const f16* __restrict__ vlp,
                                                   float* __restrict__ Mo) {
    __shared__ float Mbuf[4][64];
    const int tid = threadIdx.x, w = tid >> 6, lane = tid & 63;
    const int quad = lane >> 4, l15 = lane & 15;
    const int bid0 = blockIdx.y * 32 + blockIdx.x;
    const int swz  = (bid0 & 7) * 64 + (bid0 >> 3);
    const int q0 = (swz & 31) * 64, head = swz >> 5;
    const f16* Ah_g = uhp + (size_t)head * 2048 * 96;
    const f16* Al_g = ulp + (size_t)head * 2048 * 96;

    f16x8 Afh[4][3], Afl[4][3];
#pragma unroll
    for (int mt = 0; mt < 4; ++mt)
#pragma unroll
        for (int cc = 0; cc < 3; ++cc) {
            size_t off = (size_t)(q0 + 16 * mt + l15) * 96 + cc * 32 + quad * 8;
            Afh[mt][cc] = *(const f16x8*)(Ah_g + off);
            Afl[mt][cc] = *(const f16x8*)(Al_g + off);
        }

    const f16* Bh_p = vhp + (size_t)head * 2048 * 96 + (size_t)(w * 16 + l15) * 96 + quad * 8;
    const f16* Bl_p = vlp + (size_t)head * 2048 * 96 + (size_t)(w * 16 + l15) * 96 + quad * 8;

    f16x8 Bch[2][3], Bcl[2][3];
#pragma unroll
    for (int cc = 0; cc < 3; ++cc) {
        Bch[0][cc] = *(const f16x8*)(Bh_p + cc * 32);
        Bcl[0][cc] = *(const f16x8*)(Bl_p + cc * 32);
    }

    float m_run[4][4];
#pragma unroll
    for (int mt = 0; mt < 4; ++mt)
#pragma unroll
        for (int r = 0; r < 4; ++r) m_run[mt][r] = -3.0e38f;

    for (int tp = 0; tp < 16; ++tp) {
#pragma unroll
        for (int h = 0; h < 2; ++h) {
            const int t = 2 * tp + h;
            if (t < 31) {
                const f16* bh = Bh_p + (size_t)(t + 1) * 6144;
                const f16* bl = Bl_p + (size_t)(t + 1) * 6144;
#pragma unroll
                for (int cc = 0; cc < 3; ++cc) {
                    Bch[h ^ 1][cc] = *(const f16x8*)(bh + cc * 32);
                    Bcl[h ^ 1][cc] = *(const f16x8*)(bl + cc * 32);
                }
            }
            f32x4 accS[4] = {}, accX[4] = {};
            __builtin_amdgcn_s_setprio(1);
#pragma unroll
            for (int cc = 0; cc < 3; ++cc)
#pragma unroll
                for (int mt = 0; mt < 4; ++mt) {
                    accS[mt] = MFMA16(Afh[mt][cc], Bch[h][cc], accS[mt]);
                    accX[mt] = MFMA16(Afh[mt][cc], Bcl[h][cc], accX[mt]);
                    accX[mt] = MFMA16(Afl[mt][cc], Bch[h][cc], accX[mt]);
                }
            __builtin_amdgcn_s_setprio(0);
#pragma unroll
            for (int mt = 0; mt < 4; ++mt)
#pragma unroll
                for (int r = 0; r < 4; ++r) {
                    float zl = fmaf(ZC1, accS[mt][r], ZC2 * accX[mt][r]);
                    m_run[mt][r] = fmaxf(m_run[mt][r], zl);
                }
        }
    }
#pragma unroll
    for (int mt = 0; mt < 4; ++mt)
#pragma unroll
        for (int r = 0; r < 4; ++r) {
            float m = m_run[mt][r];
            m = fmaxf(m, __shfl_xor(m, 1)); m = fmaxf(m, __shfl_xor(m, 2));
            m = fmaxf(m, __shfl_xor(m, 4)); m = fmaxf(m, __shfl_xor(m, 8));
            m_run[mt][r] = m;
        }
    if (l15 == 0) {
#pragma unroll
        for (int mt = 0; mt < 4; ++mt)
#pragma unroll
            for (int r = 0; r < 4; ++r)
                Mbuf[w][16 * mt + 4 * quad + r] = m_run[mt][r];
    }
    __syncthreads();
    if (tid < 64) {
        float M = -3.0e38f;
#pragma unroll
        for (int ww = 0; ww < 4; ++ww) M = fmaxf(M, Mbuf[ww][tid]);
        Mo[head * 2048 + q0 + tid] = M;      // log2-domain exact row max
    }
}

// ============================================================
// K3a: S=ur.vr^T, P=exp2(zl-M[q]), out=P@vr + ones-column row sums
// (L), /L, rope_o -> w1; writes Lo. Direct-global B-frags with
// 1-tile-ahead prefetch; P and Vt double-buffered in LDS -> ONE
// barrier per tile. P stored with rotation col'=(col+16*quad)&63.
// (round-8 proven)
// ============================================================
__global__ __launch_bounds__(256, 2) void k3a(const f16* __restrict__ uhp,
                                              const f16* __restrict__ ulp,
                                              const f16* __restrict__ vhp,
                                              const f16* __restrict__ vlp,
                                              const f16* __restrict__ vT,
                                              const float* __restrict__ Mo,
                                              float* __restrict__ Lo,
                                              const float* __restrict__ cosb,
                                              const float* __restrict__ sinb,
                                              f16* __restrict__ w1) {
    __shared__ f16 Vt[2][112 * 72];    // rows 96..111 = ones (row-sum block)
    __shared__ f16 P[2][64 * 72];
    const int tid = threadIdx.x, w = tid >> 6, lane = tid & 63;
    const int quad = lane >> 4, l15 = lane & 15;
    const int bid0 = blockIdx.y * 32 + blockIdx.x;
    const int swz  = (bid0 & 7) * 64 + (bid0 >> 3);
    const int q0 = (swz & 31) * 64, head = swz >> 5;
    const f16* Ah_g = uhp + (size_t)head * 2048 * 96;
    const f16* Al_g = ulp + (size_t)head * 2048 * 96;
    const f16* Vt_g = vT + (size_t)head * 96 * 2048;

    f16x8 Afh[4][3], Afl[4][3];
#pragma unroll
    for (int mt = 0; mt < 4; ++mt)
#pragma unroll
        for (int cc = 0; cc < 3; ++cc) {
            size_t off = (size_t)(q0 + 16 * mt + l15) * 96 + cc * 32 + quad * 8;
            Afh[mt][cc] = *(const f16x8*)(Ah_g + off);
            Afl[mt][cc] = *(const f16x8*)(Al_g + off);
        }
    float negM[4][4];
#pragma unroll
    for (int mt = 0; mt < 4; ++mt)
#pragma unroll
        for (int r = 0; r < 4; ++r)
            negM[mt][r] = -Mo[head * 2048 + q0 + 16 * mt + 4 * quad + r];

    const f16* Bh_p = vhp + (size_t)head * 2048 * 96 + (size_t)(w * 16 + l15) * 96 + quad * 8;
    const f16* Bl_p = vlp + (size_t)head * 2048 * 96 + (size_t)(w * 16 + l15) * 96 + quad * 8;
    const int vr0 = tid >> 3, vc8 = (tid & 7) * 8;       // Vt rows vr0,+32,+64
    const int pwc = (w * 16 + l15 + 16 * quad) & 63;     // P write col (rotated)
    const int prr = 16 * (l15 >> 2);                     // P read rotation

    // ones rows for the row-sum MFMA (both buffers, written once)
    if (tid < 144) {
        f16x8 ones = {(f16)1, (f16)1, (f16)1, (f16)1,
                      (f16)1, (f16)1, (f16)1, (f16)1};
        *(f16x8*)&Vt[0][96 * 72 + tid * 8] = ones;
        *(f16x8*)&Vt[1][96 * 72 + tid * 8] = ones;
    }

    f16x8 Bch[2][3], Bcl[2][3];
    float4 v0, v1, v2;
    // prologue: tile 0
#pragma unroll
    for (int cc = 0; cc < 3; ++cc) {
        Bch[0][cc] = *(const f16x8*)(Bh_p + cc * 32);
        Bcl[0][cc] = *(const f16x8*)(Bl_p + cc * 32);
    }
    v0 = *(const float4*)(Vt_g + (size_t)vr0 * 2048 + vc8);
    v1 = *(const float4*)(Vt_g + (size_t)(vr0 + 32) * 2048 + vc8);
    v2 = *(const float4*)(Vt_g + (size_t)(vr0 + 64) * 2048 + vc8);
    *(float4*)&Vt[0][vr0 * 72 + vc8] = v0;
    *(float4*)&Vt[0][(vr0 + 32) * 72 + vc8] = v1;
    *(float4*)&Vt[0][(vr0 + 64) * 72 + vc8] = v2;

    f32x4 accO[7] = {};

    for (int tp = 0; tp < 16; ++tp) {
#pragma unroll
        for (int h = 0; h < 2; ++h) {
            const int t = 2 * tp + h;
            if (t < 31) {             // prefetch tile t+1 (hides under S-MFMA)
                const f16* bh = Bh_p + (size_t)(t + 1) * 6144;
                const f16* bl = Bl_p + (size_t)(t + 1) * 6144;
                const int kn = (t + 1) * 64;
#pragma unroll
                for (int cc = 0; cc < 3; ++cc) {
                    Bch[h ^ 1][cc] = *(const f16x8*)(bh + cc * 32);
                    Bcl[h ^ 1][cc] = *(const f16x8*)(bl + cc * 32);
                }
                v0 = *(const float4*)(Vt_g + (size_t)vr0 * 2048 + kn + vc8);
                v1 = *(const float4*)(Vt_g + (size_t)(vr0 + 32) * 2048 + kn + vc8);
                v2 = *(const float4*)(Vt_g + (size_t)(vr0 + 64) * 2048 + kn + vc8);
            }
            f32x4 accS[4] = {}, accX[4] = {};
            __builtin_amdgcn_s_setprio(1);
#pragma unroll
            for (int cc = 0; cc < 3; ++cc)
#pragma unroll
                for (int mt = 0; mt < 4; ++mt) {
                    accS[mt] = MFMA16(Afh[mt][cc], Bch[h][cc], accS[mt]);
                    accX[mt] = MFMA16(Afh[mt][cc], Bcl[h][cc], accX[mt]);
                    accX[mt] = MFMA16(Afl[mt][cc], Bch[h][cc], accX[mt]);
                }
            __builtin_amdgcn_s_setprio(0);
#pragma unroll
            for (int mt = 0; mt < 4; ++mt)
#pragma unroll
                for (int r = 0; r < 4; ++r) {
                    float zl = fmaf(ZC1, accS[mt][r], ZC2 * accX[mt][r]);
                    P[h][(16 * mt + 4 * quad + r) * 72 + pwc] =
                        (f16)exp2f(zl + negM[mt][r]);
                }
            __syncthreads();          // the single per-tile barrier
            __builtin_amdgcn_s_setprio(1);
#pragma unroll
            for (int kc = 0; kc < 2; ++kc) {
                f16x8 ap = *(const f16x8*)&P[h][(w * 16 + l15) * 72 +
                                               ((kc * 32 + quad * 8 + prr) & 63)];
#pragma unroll
                for (int nt = 0; nt < 7; ++nt) {   // nt=6: ones rows -> L
                    f16x8 bv = *(const f16x8*)&Vt[h][(nt * 16 + l15) * 72 + kc * 32 + quad * 8];
                    accO[nt] = MFMA16(ap, bv, accO[nt]);
                }
            }
            __builtin_amdgcn_s_setprio(0);
            if (t < 31) {             // stage Vt(t+1) into the other buffer
                *(float4*)&Vt[h ^ 1][vr0 * 72 + vc8] = v0;
                *(float4*)&Vt[h ^ 1][(vr0 + 32) * 72 + vc8] = v1;
                *(float4*)&Vt[h ^ 1][(vr0 + 64) * 72 + vc8] = v2;
            }
        }
    }
    float invL[4];
#pragma unroll
    for (int r = 0; r < 4; ++r) invL[r] = 1.0f / accO[6][r];
    if (l15 == 0) {
#pragma unroll
        for (int r = 0; r < 4; ++r)
            Lo[head * 2048 + q0 + w * 16 + quad * 4 + r] = accO[6][r];
    }

    const int b = head >> 3, c = head & 7;
#pragma unroll
    for (int r = 0; r < 4; ++r) {
        int q = q0 + w * 16 + quad * 4 + r;
        int cbi = (b * 2048 + q) * 96;
        f16* wrow = w1 + (size_t)(b * 2048 + q) * 768 + c * 96;
#pragma unroll
        for (int nt = 0; nt < 3; ++nt) {
            int rr = nt * 16 + l15;
            float cc = cosb[cbi + rr], ss = sinb[cbi + rr];
            float a = accO[nt][r] * invL[r];
            float b2 = accO[nt + 3][r] * invL[r];
            wrow[rr] = (f16)(a * cc + b2 * ss);
            wrow[rr + 48] = (f16)(b2 * cc - a * ss);
        }
    }
}

// ============================================================
// K3b: S2[q][k]=vr_q.ur_k, P2=exp2(zl-M[k])/L[k], out=P2@uo,
// rope -> w2. Same 1-barrier direct-B pipeline as k3a. (round-8)
// ============================================================
__global__ __launch_bounds__(256, 2) void k3b(const f16* __restrict__ uhp,
                                              const f16* __restrict__ ulp,
                                              const f16* __restrict__ vhp,
                                              const f16* __restrict__ vlp,
                                              const f16* __restrict__ oT,
                                              const float* __restrict__ Mo,
                                              const float* __restrict__ Lo,
                                              const float* __restrict__ cosb,
                                              const float* __restrict__ sinb,
                                              f16* __restrict__ w2) {
    __shared__ f16 Ot[2][96 * 72];
    __shared__ f16 P[2][64 * 72];
    const int tid = threadIdx.x, w = tid >> 6, lane = tid & 63;
    const int quad = lane >> 4, l15 = lane & 15;
    const int bid0 = blockIdx.y * 32 + blockIdx.x;
    const int swz  = (bid0 & 7) * 64 + (bid0 >> 3);
    const int q0 = (swz & 31) * 64, head = swz >> 5;
    const f16* Ah_g = vhp + (size_t)head * 2048 * 96;   // A = vr
    const f16* Al_g = vlp + (size_t)head * 2048 * 96;
    const f16* Ot_g = oT + (size_t)head * 96 * 2048;

    f16x8 Afh[4][3], Afl[4][3];
#pragma unroll
    for (int mt = 0; mt < 4; ++mt)
#pragma unroll
        for (int cc = 0; cc < 3; ++cc) {
            size_t off = (size_t)(q0 + 16 * mt + l15) * 96 + cc * 32 + quad * 8;
            Afh[mt][cc] = *(const f16x8*)(Ah_g + off);
            Afl[mt][cc] = *(const f16x8*)(Al_g + off);
        }

    const f16* Bh_p = uhp + (size_t)head * 2048 * 96 + (size_t)(w * 16 + l15) * 96 + quad * 8;
    const f16* Bl_p = ulp + (size_t)head * 2048 * 96 + (size_t)(w * 16 + l15) * 96 + quad * 8;
    const int vr0 = tid >> 3, vc8 = (tid & 7) * 8;
    const int pwc = (w * 16 + l15 + 16 * quad) & 63;
    const int prr = 16 * (l15 >> 2);

    f16x8 Bch[2][3], Bcl[2][3];
    float4 v0, v1, v2;
#pragma unroll
    for (int cc = 0; cc < 3; ++cc) {
        Bch[0][cc] = *(const f16x8*)(Bh_p + cc * 32);
        Bcl[0][cc] = *(const f16x8*)(Bl_p + cc * 32);
    }
    v0 = *(const float4*)(Ot_g + (size_t)vr0 * 2048 + vc8);
    v1 = *(const float4*)(Ot_g + (size_t)(vr0 + 32) * 2048 + vc8);
    v2 = *(const float4*)(Ot_g + (size_t)(vr0 + 64) * 2048 + vc8);
    *(float4*)&Ot[0][vr0 * 72 + vc8] = v0;
    *(float4*)&Ot[0][(vr0 + 32) * 72 + vc8] = v1;
    *(float4*)&Ot[0][(vr0 + 64) * 72 + vc8] = v2;

    f32x4 accO[6] = {};

    for (int tp = 0; tp < 16; ++tp) {
#pragma unroll
        for (int h = 0; h < 2; ++h) {
            const int t = 2 * tp + h;
            const int k0 = t * 64;
            float negMk = -Mo[head * 2048 + k0 + w * 16 + l15];
            float invLk = 1.0f / Lo[head * 2048 + k0 + w * 16 + l15];
            if (t < 31) {
                const f16* bh = Bh_p + (size_t)(t + 1) * 6144;
                const f16* bl = Bl_p + (size_t)(t + 1) * 6144;
                const int kn = (t + 1) * 64;
#pragma unroll
                for (int cc = 0; cc < 3; ++cc) {
                    Bch[h ^ 1][cc] = *(const f16x8*)(bh + cc * 32);
                    Bcl[h ^ 1][cc] = *(const f16x8*)(bl + cc * 32);
                }
                v0 = *(const float4*)(Ot_g + (size_t)vr0 * 2048 + kn + vc8);
                v1 = *(const float4*)(Ot_g + (size_t)(vr0 + 32) * 2048 + kn + vc8);
                v2 = *(const float4*)(Ot_g + (size_t)(vr0 + 64) * 2048 + kn + vc8);
            }
            f32x4 accS[4] = {}, accX[4] = {};
            __builtin_amdgcn_s_setprio(1);
#pragma unroll
            for (int cc = 0; cc < 3; ++cc)
#pragma unroll
                for (int mt = 0; mt < 4; ++mt) {
                    accS[mt] = MFMA16(Afh[mt][cc], Bch[h][cc], accS[mt]);
                    // preserve cross-product order: (u_hi*v_lo) first, then (u_lo*v_hi)
                    accX[mt] = MFMA16(Afl[mt][cc], Bch[h][cc], accX[mt]);   // v_lo * u_hi
                    accX[mt] = MFMA16(Afh[mt][cc], Bcl[h][cc], accX[mt]);   // v_hi * u_lo
                }
            __builtin_amdgcn_s_setprio(0);
#pragma unroll
            for (int mt = 0; mt < 4; ++mt)
#pragma unroll
                for (int r = 0; r < 4; ++r) {
                    float zl = fmaf(ZC1, accS[mt][r], ZC2 * accX[mt][r]);
                    P[h][(16 * mt + 4 * quad + r) * 72 + pwc] =
                        (f16)(exp2f(zl + negMk) * invLk);
                }
            __syncthreads();
            __builtin_amdgcn_s_setprio(1);
#pragma unroll
            for (int kc = 0; kc < 2; ++kc) {
                f16x8 ap = *(const f16x8*)&P[h][(w * 16 + l15) * 72 +
                                               ((kc * 32 + quad * 8 + prr) & 63)];
#pragma unroll
                for (int nt = 0; nt < 6; ++nt) {
                    f16x8 bo = *(const f16x8*)&Ot[h][(nt * 16 + l15) * 72 + kc * 32 + quad * 8];
                    accO[nt] = MFMA16(ap, bo, accO[nt]);
                }
            }
            __builtin_amdgcn_s_setprio(0);
            if (t < 31) {
                *(float4*)&Ot[h ^ 1][vr0 * 72 + vc8] = v0;
                *(float4*)&Ot[h ^ 1][(vr0 + 32) * 72 + vc8] = v1;
                *(float4*)&Ot[h ^ 1][(vr0 + 64) * 72 + vc8] = v2;
            }
        }
    }
    const int b = head >> 3, c = head & 7;
#pragma unroll
    for (int r = 0; r < 4; ++r) {
        int q = q0 + w * 16 + quad * 4 + r;
        int cbi = (b * 2048 + q) * 96;
        f16* wrow = w2 + (size_t)(b * 2048 + q) * 768 + c * 96;
#pragma unroll
        for (int nt = 0; nt < 3; ++nt) {
            int rr = nt * 16 + l15;
            float cc = cosb[cbi + rr], ss = sinb[cbi + rr];
            float a = accO[nt][r];
            float b2 = accO[nt + 3][r];
            wrow[rr] = (f16)(a * cc - b2 * ss);
            wrow[rr + 48] = (f16)(b2 * cc + a * ss);
        }
    }
}

// ============================================================
// K4: G = w1@U + w2@V (fp16 MFMA). + XCD d-panel clustering:
// each XCD owns a contiguous 48-block range -> <=2 U/V panels
// (L2-resident) and localized w1/w2 re-reads. (the one change
// kept from rounds 9-11; pure bijective index remap)
// ============================================================
__global__ __launch_bounds__(256, 2) void k4_final(const f16* __restrict__ w1,
                                                   const f16* __restrict__ w2,
                                                   const float* __restrict__ U,
                                                   const float* __restrict__ V,
                                                   float* __restrict__ outp) {
    __shared__ f16 A1[128 * 56];
    __shared__ f16 A2[128 * 56];
    __shared__ f16 B1[64 * 56];
    __shared__ f16 B2[64 * 56];
    const int tid = threadIdx.x, w = tid >> 6, lane = tid & 63;
    const int quad = lane >> 4, l15 = lane & 15;
    const int id = blockIdx.y * 32 + blockIdx.x;         // 0..383
    const int g  = (id & 7) * 48 + (id >> 3);            // XCD-clustered, bijective
    const int bs0 = (g & 31) * 128;
    const int d0 = (g >> 5) * 64;
    f32x4 acc[2][4] = {};

    for (int ec = 0; ec < 24; ++ec) {
        int e0 = ec * 32;
        __syncthreads();
#pragma unroll
        for (int m = 0; m < 2; ++m) {
            int f = tid + 256 * m;
            int row = f >> 2, q = f & 3;
            *(float4*)&A1[row * 56 + q * 8] =
                *(const float4*)(w1 + (size_t)(bs0 + row) * 768 + e0 + q * 8);
            *(float4*)&A2[row * 56 + q * 8] =
                *(const float4*)(w2 + (size_t)(bs0 + row) * 768 + e0 + q * 8);
        }
#pragma unroll
        for (int m2 = 0; m2 < 2; ++m2) {
            int e_r = (tid >> 4) + 16 * m2;
            int dc = tid & 15;
            float4 fu = *(const float4*)(U + (size_t)(e0 + e_r) * 768 + d0 + dc * 4);
            float4 fv = *(const float4*)(V + (size_t)(e0 + e_r) * 768 + d0 + dc * 4);
            B1[(dc * 4 + 0) * 56 + e_r] = (f16)fu.x;
            B1[(dc * 4 + 1) * 56 + e_r] = (f16)fu.y;
            B1[(dc * 4 + 2) * 56 + e_r] = (f16)fu.z;
            B1[(dc * 4 + 3) * 56 + e_r] = (f16)fu.w;
            B2[(dc * 4 + 0) * 56 + e_r] = (f16)fv.x;
            B2[(dc * 4 + 1) * 56 + e_r] = (f16)fv.y;
            B2[(dc * 4 + 2) * 56 + e_r] = (f16)fv.z;
            B2[(dc * 4 + 3) * 56 + e_r] = (f16)fv.w;
        }
        __syncthreads();
        f16x8 a1f[2], a2f[2];
#pragma unroll
        for (int mt = 0; mt < 2; ++mt) {
            a1f[mt] = *(const f16x8*)&A1[(32 * w + 16 * mt + l15) * 56 + quad * 8];
            a2f[mt] = *(const f16x8*)&A2[(32 * w + 16 * mt + l15) * 56 + quad * 8];
        }
#pragma unroll
        for (int nt = 0; nt < 4; ++nt) {
            f16x8 b1f = *(const f16x8*)&B1[(nt * 16 + l15) * 56 + quad * 8];
            f16x8 b2f = *(const f16x8*)&B2[(nt * 16 + l15) * 56 + quad * 8];
#pragma unroll
            for (int mt = 0; mt < 2; ++mt) {
                acc[mt][nt] = MFMA16(a1f[mt], b1f, acc[mt][nt]);
                acc[mt][nt] = MFMA16(a2f[mt], b2f, acc[mt][nt]);
            }
        }
    }
#pragma unroll
    for (int mt = 0; mt < 2; ++mt)
#pragma unroll
        for (int nt = 0; nt < 4; ++nt)
#pragma unroll
            for (int r = 0; r < 4; ++r) {
                int s = bs0 + 32 * w + 16 * mt + 4 * quad + r;
                int d = d0 + 16 * nt + l15;
                outp[(size_t)s * 768 + d] = acc[mt][nt][r];
            }
}

extern "C" void kernel_launch(void* const* d_in, const int* in_sizes, int n_in,
                              void* d_out, int out_size, void* d_ws, size_t ws_size,
                              hipStream_t stream) {
    const float* qz   = (const float*)d_in[0];
    const float* cosb = (const float*)d_in[1];
    const float* sinb = (const float*)d_in[2];
    const float* U    = (const float*)d_in[3];
    const float* V    = (const float*)d_in[4];
    float* outp = (float*)d_out;

    f16* ws16 = (f16*)d_ws;
    f16* uhp = ws16;
    f16* ulp = ws16 + HN;
    f16* vhp = ws16 + 2 * HN;
    f16* vlp = ws16 + 3 * HN;
    f16* vT  = ws16 + 4 * HN;
    f16* oT  = ws16 + 5 * HN;
    f16* w1  = ws16 + 6 * HN;
    f16* w2  = ws16 + 7 * HN;
    float* Mo = (float*)(ws16 + 8 * HN);
    float* Lo = Mo + 16 * 2048;

    // qz hi/lo splits live in the w1/w2 slots (dead until k3a/k3b write them).
    f16* qzh = w1;
    f16* qzl = w2;
    // U/V hi/lo splits live in d_out scratch (overwritten by k4 at the end).
    f16* outw = (f16*)d_out;
    f16* Uh = outw;
    f16* Ul = outw + UVN;
    f16* Vh = outw + 2 * UVN;
    f16* Vl = outw + 3 * UVN;

    k0_split<<<dim3(3072), 256, 0, stream>>>(qz, U, V, qzh, qzl, Uh, Ul, Vh, Vl);
    k1_proj<<<dim3(64, 8), 256, 0, stream>>>(qzh, qzl, Uh, Ul, Vh, Vl, cosb, sinb,
                                             uhp, ulp, vhp, vlp, vT, oT);
    k2_stats<<<dim3(32, 16), 256, 0, stream>>>(uhp, ulp, vhp, vlp, Mo);
    k3a<<<dim3(32, 16), 256, 0, stream>>>(uhp, ulp, vhp, vlp, vT, Mo, Lo, cosb, sinb, w1);
    k3b<<<dim3(32, 16), 256, 0, stream>>>(uhp, ulp, vhp, vlp, oT, Mo, Lo, cosb, sinb, w2);
    k4_final<<<dim3(32, 12), 256, 0, stream>>>(w1, w2, U, V, outp);
}